// Round 5
// baseline (1784.369 us; speedup 1.0000x reference)
//
#include <hip/hip_runtime.h>
#include <hip/hip_bf16.h>

#define NN 50000
#define EE 800000

typedef __attribute__((ext_vector_type(8))) short short8v;
typedef __attribute__((ext_vector_type(4))) float f32x4;

__device__ __forceinline__ float bf2f(unsigned short u) {
    return __uint_as_float(((unsigned int)u) << 16);
}
__device__ __forceinline__ unsigned short f2bf(float f) {
    unsigned int u = __float_as_uint(f);
    unsigned int r = 0x7FFF + ((u >> 16) & 1);
    return (unsigned short)((u + r) >> 16);
}

// ---------------- fp32 -> bf16 conversion (vectorized) ----------------
__global__ void cvt_f2bf(const float* __restrict__ in, unsigned short* __restrict__ out, int n4) {
    int i = blockIdx.x * 256 + threadIdx.x;
    if (i >= n4) return;
    float4 v = reinterpret_cast<const float4*>(in)[i];
    ushort4 o;
    o.x = f2bf(v.x); o.y = f2bf(v.y); o.z = f2bf(v.z); o.w = f2bf(v.w);
    reinterpret_cast<ushort4*>(out)[i] = o;
}

// ---------------- CSR construction ----------------
__global__ void count_k(const int* __restrict__ dst, int* __restrict__ cursor) {
    int i = blockIdx.x * 256 + threadIdx.x;
    if (i >= 2 * EE) return;
    int r = (i >= EE) ? 1 : 0;
    atomicAdd(&cursor[r * NN + dst[i]], 1);
}

__global__ __launch_bounds__(1024) void scan_k(int* __restrict__ cursor, int* __restrict__ rowptr) {
    int r = blockIdx.x;
    int* cnt = cursor + r * NN;          // counts in, exclusive prefix out
    int* rp  = rowptr + r * (NN + 1);
    int tid = threadIdx.x;
    const int CH = (NN + 1023) / 1024;   // 49
    int beg = tid * CH;
    int end = beg + CH; if (end > NN) end = NN;
    int s = 0;
    for (int i = beg; i < end && i < NN; ++i) s += cnt[i];
    __shared__ int sums[1024];
    sums[tid] = s;
    __syncthreads();
    for (int offd = 1; offd < 1024; offd <<= 1) {
        int v = 0;
        if (tid >= offd) v = sums[tid - offd];
        __syncthreads();
        sums[tid] += v;
        __syncthreads();
    }
    int run = sums[tid] - s;             // exclusive offset for this chunk
    for (int i = beg; i < end && i < NN; ++i) {
        int c = cnt[i];
        rp[i] = run;
        cnt[i] = run;                    // cursor for scatter
        run += c;
    }
    if (tid == 1023) rp[NN] = sums[1023];
}

__global__ void scatter_k(const int* __restrict__ src, const int* __restrict__ dst,
                          int* __restrict__ cursor, int* __restrict__ csr) {
    int i = blockIdx.x * 256 + threadIdx.x;
    if (i >= 2 * EE) return;
    int r = (i >= EE) ? 1 : 0;
    int pos = atomicAdd(&cursor[r * NN + dst[i]], 1);
    csr[r * EE + pos] = src[i];
}

// ---------------- MFMA GEMM: C[n,o] = sum_k A[n,k]*W[o,k]; A,W bf16; K=256 ----------------
template<bool BF16OUT>
__global__ __launch_bounds__(256) void gemm_mfma(
    const unsigned short* __restrict__ A,   // [M][256] bf16
    const unsigned short* __restrict__ W,   // per-rel [256][256] bf16
    void* __restrict__ Cout, int relW, long relC, int M)
{
    __shared__ unsigned short sA[128][72];  // 64-k chunk, stride 72 (2-way bank alias = free)
    __shared__ unsigned short sB[128][72];
    const int K = 256;
    int tid = threadIdx.x;
    int wid = tid >> 6, lane = tid & 63;
    int wr = wid >> 1, wc = wid & 1;
    int n0 = blockIdx.x * 128;
    int o0 = blockIdx.y * 128;
    const unsigned short* Wr = W + (size_t)blockIdx.z * relW;

    f32x4 acc[4][4] = {};

    for (int k0 = 0; k0 < K; k0 += 64) {
        #pragma unroll
        for (int p = 0; p < 4; ++p) {
            int flat = p * 256 + tid;            // 0..1023
            int row = flat >> 3, k8 = (flat & 7) * 8;
            int gr = n0 + row;
            short8v va = {0, 0, 0, 0, 0, 0, 0, 0};
            if (gr < M) va = *reinterpret_cast<const short8v*>(A + (size_t)gr * K + k0 + k8);
            *reinterpret_cast<short8v*>(&sA[row][k8]) = va;
            short8v vb = *reinterpret_cast<const short8v*>(Wr + (size_t)(o0 + row) * K + k0 + k8);
            *reinterpret_cast<short8v*>(&sB[row][k8]) = vb;
        }
        __syncthreads();
        #pragma unroll
        for (int kk = 0; kk < 2; ++kk) {
            short8v af[4], bf[4];
            int klo = kk * 32 + (lane >> 4) * 8;
            #pragma unroll
            for (int m = 0; m < 4; ++m)
                af[m] = *reinterpret_cast<const short8v*>(&sA[wr * 64 + m * 16 + (lane & 15)][klo]);
            #pragma unroll
            for (int n = 0; n < 4; ++n)
                bf[n] = *reinterpret_cast<const short8v*>(&sB[wc * 64 + n * 16 + (lane & 15)][klo]);
            #pragma unroll
            for (int m = 0; m < 4; ++m)
                #pragma unroll
                for (int n = 0; n < 4; ++n)
                    acc[m][n] = __builtin_amdgcn_mfma_f32_16x16x32_bf16(af[m], bf[n], acc[m][n], 0, 0, 0);
        }
        __syncthreads();
    }
    int col0 = o0 + wc * 64;
    int rbase = (lane >> 4) * 4;
    #pragma unroll
    for (int m = 0; m < 4; ++m) {
        #pragma unroll
        for (int j = 0; j < 4; ++j) {
            int gr = n0 + wr * 64 + m * 16 + rbase + j;
            if (gr >= M) continue;
            #pragma unroll
            for (int n = 0; n < 4; ++n) {
                int gc = col0 + n * 16 + (lane & 15);
                size_t idx = (size_t)blockIdx.z * relC + (size_t)gr * 256 + gc;
                if constexpr (BF16OUT) ((unsigned short*)Cout)[idx] = f2bf(acc[m][n][j]);
                else                   ((float*)Cout)[idx] = acc[m][n][j];
            }
        }
    }
}

// ---------------- Layer-1 edge softmax + aggregation (H=4, D=64) ----------------
// Persistent work-stealing waves: 4-wave WGs reach full occupancy, per-wave node
// pull decouples retirement (R3 lesson). Direct exp, no running max (scores O(1)).
__global__ __launch_bounds__(256) void agg1_k(
    const unsigned short* __restrict__ feat,   // [2][NN][256] bf16
    const unsigned short* __restrict__ xb,     // [NN][256] bf16 (residual)
    const float* __restrict__ a1,              // [2][256]
    const float* __restrict__ b1,              // [2][256]
    const int* __restrict__ rowptr, const int* __restrict__ csr,
    unsigned short* __restrict__ hb,           // [NN][256] bf16 out
    int* __restrict__ counter)
{
    int lane = threadIdx.x & 63;
    unsigned laneoff = (unsigned)lane * 8u;    // byte offset of this lane's ushort4 in a 512B row
    int c = lane * 4;
    // hoisted lane-only coefficients
    float4 av0v = *reinterpret_cast<const float4*>(a1 + c);
    float4 av1v = *reinterpret_cast<const float4*>(a1 + 256 + c);
    float p6[2][4], q4[2][4];
    p6[0][0] = 0.6f * av0v.x; q4[0][0] = 0.4f * av0v.x;
    p6[0][1] = 0.6f * av0v.y; q4[0][1] = 0.4f * av0v.y;
    p6[0][2] = 0.6f * av0v.z; q4[0][2] = 0.4f * av0v.z;
    p6[0][3] = 0.6f * av0v.w; q4[0][3] = 0.4f * av0v.w;
    p6[1][0] = 0.6f * av1v.x; q4[1][0] = 0.4f * av1v.x;
    p6[1][1] = 0.6f * av1v.y; q4[1][1] = 0.4f * av1v.y;
    p6[1][2] = 0.6f * av1v.z; q4[1][2] = 0.4f * av1v.z;
    p6[1][3] = 0.6f * av1v.w; q4[1][3] = 0.4f * av1v.w;
    float bsum0 = b1[c + 0] + b1[256 + c + 0];
    float bsum1 = b1[c + 1] + b1[256 + c + 1];
    float bsum2 = b1[c + 2] + b1[256 + c + 2];
    float bsum3 = b1[c + 3] + b1[256 + c + 3];

    while (true) {
        int n;
        if (lane == 0) n = atomicAdd(counter, 1);
        n = __shfl(n, 0);
        if (n >= NN) break;

        float t0 = 0.f, t1 = 0.f, t2 = 0.f, t3 = 0.f;
        #pragma unroll
        for (int r = 0; r < 2; ++r) {
            const char* frB = (const char*)(feat + (size_t)r * NN * 256);
            ushort4 ud = *reinterpret_cast<const ushort4*>(frB + (((unsigned)n << 9) | laneoff));
            float fd0 = bf2f(ud.x), fd1 = bf2f(ud.y), fd2 = bf2f(ud.z), fd3 = bf2f(ud.w);
            float lsum = 0.f;
            float a0 = 0.f, a1v = 0.f, a2v = 0.f, a3 = 0.f;
            int beg = rowptr[r * (NN + 1) + n], end = rowptr[r * (NN + 1) + n + 1];
            const int* cp = csr + (size_t)r * EE;
            for (int e = beg; e < end; ++e) {
                int s = cp[e];
                ushort4 us = *reinterpret_cast<const ushort4*>(frB + (((unsigned)s << 9) | laneoff));
                float fs0 = bf2f(us.x), fs1 = bf2f(us.y), fs2 = bf2f(us.z), fs3 = bf2f(us.w);
                float t, part;
                t = fs0 + fd0; part  = p6[r][0] * t + q4[r][0] * fabsf(t);
                t = fs1 + fd1; part += p6[r][1] * t; part += q4[r][1] * fabsf(t);
                t = fs2 + fd2; part += p6[r][2] * t; part += q4[r][2] * fabsf(t);
                t = fs3 + fd3; part += p6[r][3] * t; part += q4[r][3] * fabsf(t);
                part += __shfl_xor(part, 1);
                part += __shfl_xor(part, 2);
                part += __shfl_xor(part, 4);
                part += __shfl_xor(part, 8);
                float p = __expf(part);
                lsum += p;
                a0  += p * fs0;
                a1v += p * fs1;
                a2v += p * fs2;
                a3  += p * fs3;
            }
            float inv = 1.f / fmaxf(lsum, 1e-16f);
            t0 += a0 * inv; t1 += a1v * inv; t2 += a2v * inv; t3 += a3 * inv;
        }
        unsigned o = ((unsigned)n << 8) + (unsigned)c;
        ushort4 xv4 = *reinterpret_cast<const ushort4*>(xb + o);
        float v0 = fmaxf(t0 + 2.f * bf2f(xv4.x) + bsum0, 0.f);
        float v1 = fmaxf(t1 + 2.f * bf2f(xv4.y) + bsum1, 0.f);
        float v2 = fmaxf(t2 + 2.f * bf2f(xv4.z) + bsum2, 0.f);
        float v3 = fmaxf(t3 + 2.f * bf2f(xv4.w) + bsum3, 0.f);
        ushort4 ho;
        ho.x = f2bf(v0); ho.y = f2bf(v1); ho.z = f2bf(v2); ho.w = f2bf(v3);
        reinterpret_cast<ushort4*>(hb)[((unsigned)n << 6) + (unsigned)lane] = ho;
    }
}

// ---------------- Layer-2 helpers ----------------
__global__ void build_wcat_bf(const float* __restrict__ W2, const float* __restrict__ Wres2,
                              unsigned short* __restrict__ Wcat) {
    int i = blockIdx.x * 256 + threadIdx.x;
    if (i >= 256 * 256) return;
    int o = i >> 8, k = i & 255;
    int sel = o >> 6, row = o & 63;
    int r = sel >> 1;
    const float* Wsrc = (sel & 1) ? Wres2 : W2;
    Wcat[i] = f2bf(Wsrc[((size_t)r * 64 + row) * 256 + k]);
}

__global__ void post2(const float* __restrict__ G, const float* __restrict__ b2,
                      unsigned short* __restrict__ feat2, float* __restrict__ base) {
    int i = blockIdx.x * 256 + threadIdx.x;
    if (i >= NN * 64) return;
    int n = i >> 6, d = i & 63;
    const float* g = G + (size_t)n * 256;
    feat2[i] = f2bf(g[d]);
    feat2[(size_t)NN * 64 + i] = f2bf(g[128 + d]);
    base[i] = g[64 + d] + g[192 + d] + b2[d] + b2[64 + d];
}

// ---------------- Layer-2 edge softmax + aggregation (H=1, D=64) ----------------
__global__ __launch_bounds__(256) void agg2_k(
    const unsigned short* __restrict__ feat2,  // [2][NN][64] bf16
    const float* __restrict__ base,
    const float* __restrict__ a2,              // [2][64]
    const int* __restrict__ rowptr, const int* __restrict__ csr,
    float* __restrict__ out,
    int* __restrict__ counter)
{
    int lane = threadIdx.x & 63;
    unsigned laneoff = (unsigned)lane * 2u;    // byte offset in 128B row
    float av0 = a2[lane], av1 = a2[64 + lane];
    float p6a[2] = {0.6f * av0, 0.6f * av1};
    float q4a[2] = {0.4f * av0, 0.4f * av1};

    while (true) {
        int n;
        if (lane == 0) n = atomicAdd(counter, 1);
        n = __shfl(n, 0);
        if (n >= NN) break;

        float tot = 0.f;
        #pragma unroll
        for (int r = 0; r < 2; ++r) {
            const char* frB = (const char*)(feat2 + (size_t)r * NN * 64);
            float fd = bf2f(*reinterpret_cast<const unsigned short*>(frB + (((unsigned)n << 7) | laneoff)));
            float lsum = 0.f, acc = 0.f;
            int beg = rowptr[r * (NN + 1) + n], end = rowptr[r * (NN + 1) + n + 1];
            const int* cp = csr + (size_t)r * EE;
            for (int e = beg; e < end; ++e) {
                int s = cp[e];
                float fs = bf2f(*reinterpret_cast<const unsigned short*>(frB + (((unsigned)s << 7) | laneoff)));
                float t = fs + fd;
                float part = p6a[r] * t + q4a[r] * fabsf(t);
                part += __shfl_xor(part, 1);
                part += __shfl_xor(part, 2);
                part += __shfl_xor(part, 4);
                part += __shfl_xor(part, 8);
                part += __shfl_xor(part, 16);
                part += __shfl_xor(part, 32);
                float p = __expf(part);
                lsum += p;
                acc += p * fs;
            }
            tot += acc / fmaxf(lsum, 1e-16f);
        }
        unsigned o = ((unsigned)n << 6) + (unsigned)lane;
        out[o] = fmaxf(tot + base[o], 0.f);
    }
}

extern "C" void kernel_launch(void* const* d_in, const int* in_sizes, int n_in,
                              void* d_out, int out_size, void* d_ws, size_t ws_size,
                              hipStream_t stream) {
    (void)in_sizes; (void)n_in; (void)out_size; (void)ws_size;
    const float* x     = (const float*)d_in[0];
    const int*   src   = (const int*)d_in[1];
    const int*   dst   = (const int*)d_in[2];
    const float* W1    = (const float*)d_in[3];
    const float* a1    = (const float*)d_in[4];
    const float* b1    = (const float*)d_in[5];
    const float* W2    = (const float*)d_in[6];
    const float* a2    = (const float*)d_in[7];
    const float* b2    = (const float*)d_in[8];
    const float* Wres2 = (const float*)d_in[9];
    float* out = (float*)d_out;

    char* w = (char*)d_ws;
    size_t off = 0;
    auto alloc = [&](size_t bytes) -> void* {
        void* p = w + off;
        off = (off + bytes + 255) & ~(size_t)255;
        return p;
    };
    // cursor + 2 work-stealing counters share one memset region
    int* cursor = (int*)alloc((size_t)(2 * NN + 8) * sizeof(int));
    int* counters = cursor + 2 * NN;
    int* rowptr = (int*)alloc((size_t)2 * (NN + 1) * sizeof(int));
    int* csr    = (int*)alloc((size_t)2 * EE * sizeof(int));
    unsigned short* feat1 = (unsigned short*)alloc((size_t)2 * NN * 256 * 2); // aliased as G (fp32 NN*256)
    float* G = (float*)feat1;
    unsigned short* xb = (unsigned short*)alloc((size_t)NN * 256 * 2);
    unsigned short* hb = (unsigned short*)alloc((size_t)NN * 256 * 2);
    unsigned short* W1b = (unsigned short*)alloc((size_t)2 * 256 * 256 * 2);
    unsigned short* Wcatb = (unsigned short*)alloc((size_t)256 * 256 * 2);
    unsigned short* feat2 = (unsigned short*)alloc((size_t)2 * NN * 64 * 2);
    float* base = (float*)alloc((size_t)NN * 64 * 4);

    // conversions
    cvt_f2bf<<<(NN * 256 / 4 + 255) / 256, 256, 0, stream>>>(x, xb, NN * 256 / 4);
    cvt_f2bf<<<(2 * 256 * 256 / 4 + 255) / 256, 256, 0, stream>>>(W1, W1b, 2 * 256 * 256 / 4);
    build_wcat_bf<<<(256 * 256 + 255) / 256, 256, 0, stream>>>(W2, Wres2, Wcatb);

    // CSR
    hipMemsetAsync(cursor, 0, (size_t)(2 * NN + 8) * sizeof(int), stream);
    count_k<<<(2 * EE + 255) / 256, 256, 0, stream>>>(dst, cursor);
    scan_k<<<2, 1024, 0, stream>>>(cursor, rowptr);
    scatter_k<<<(2 * EE + 255) / 256, 256, 0, stream>>>(src, dst, cursor, csr);

    // Layer 1
    dim3 g1((NN + 127) / 128, 2, 2);
    gemm_mfma<true><<<g1, 256, 0, stream>>>(xb, W1b, feat1, 256 * 256, (long)NN * 256, NN);
    agg1_k<<<2048, 256, 0, stream>>>(feat1, xb, a1, b1, rowptr, csr, hb, counters + 0);

    // Layer 2
    dim3 g2((NN + 127) / 128, 2, 1);
    gemm_mfma<false><<<g2, 256, 0, stream>>>(hb, Wcatb, G, 0, 0, NN);
    post2<<<(NN * 64 + 255) / 256, 256, 0, stream>>>(G, b2, feat2, base);
    agg2_k<<<2048, 256, 0, stream>>>(feat2, base, a2, rowptr, csr, out, counters + 4);
}

// Round 6
// 684.634 us; speedup vs baseline: 2.6063x; 2.6063x over previous
//
#include <hip/hip_runtime.h>
#include <hip/hip_bf16.h>

#define NN 50000
#define EE 800000

typedef __attribute__((ext_vector_type(8))) short short8v;
typedef __attribute__((ext_vector_type(4))) float f32x4;

__device__ __forceinline__ float bf2f(unsigned short u) {
    return __uint_as_float(((unsigned int)u) << 16);
}
__device__ __forceinline__ float bflo(unsigned int u) {
    return __uint_as_float(u << 16);
}
__device__ __forceinline__ float bfhi(unsigned int u) {
    return __uint_as_float(u & 0xffff0000u);
}
__device__ __forceinline__ unsigned short f2bf(float f) {
    unsigned int u = __float_as_uint(f);
    unsigned int r = 0x7FFF + ((u >> 16) & 1);
    return (unsigned short)((u + r) >> 16);
}

// ---------------- fp32 -> bf16 conversion (vectorized) ----------------
__global__ void cvt_f2bf(const float* __restrict__ in, unsigned short* __restrict__ out, int n4) {
    int i = blockIdx.x * 256 + threadIdx.x;
    if (i >= n4) return;
    float4 v = reinterpret_cast<const float4*>(in)[i];
    ushort4 o;
    o.x = f2bf(v.x); o.y = f2bf(v.y); o.z = f2bf(v.z); o.w = f2bf(v.w);
    reinterpret_cast<ushort4*>(out)[i] = o;
}

// ---------------- CSR construction ----------------
__global__ void count_k(const int* __restrict__ dst, int* __restrict__ cursor) {
    int i = blockIdx.x * 256 + threadIdx.x;
    if (i >= 2 * EE) return;
    int r = (i >= EE) ? 1 : 0;
    atomicAdd(&cursor[r * NN + dst[i]], 1);
}

__global__ __launch_bounds__(1024) void scan_k(int* __restrict__ cursor, int* __restrict__ rowptr) {
    int r = blockIdx.x;
    int* cnt = cursor + r * NN;          // counts in, exclusive prefix out
    int* rp  = rowptr + r * (NN + 1);
    int tid = threadIdx.x;
    const int CH = (NN + 1023) / 1024;   // 49
    int beg = tid * CH;
    int end = beg + CH; if (end > NN) end = NN;
    int s = 0;
    for (int i = beg; i < end && i < NN; ++i) s += cnt[i];
    __shared__ int sums[1024];
    sums[tid] = s;
    __syncthreads();
    for (int offd = 1; offd < 1024; offd <<= 1) {
        int v = 0;
        if (tid >= offd) v = sums[tid - offd];
        __syncthreads();
        sums[tid] += v;
        __syncthreads();
    }
    int run = sums[tid] - s;             // exclusive offset for this chunk
    for (int i = beg; i < end && i < NN; ++i) {
        int c = cnt[i];
        rp[i] = run;
        cnt[i] = run;                    // cursor for scatter
        run += c;
    }
    if (tid == 1023) rp[NN] = sums[1023];
}

__global__ void scatter_k(const int* __restrict__ src, const int* __restrict__ dst,
                          int* __restrict__ cursor, int* __restrict__ csr) {
    int i = blockIdx.x * 256 + threadIdx.x;
    if (i >= 2 * EE) return;
    int r = (i >= EE) ? 1 : 0;
    int pos = atomicAdd(&cursor[r * NN + dst[i]], 1);
    csr[r * EE + pos] = src[i];
}

// ---------------- MFMA GEMM: C[n,o] = sum_k A[n,k]*W[o,k]; A,W bf16; K=256 ----------------
template<bool BF16OUT>
__global__ __launch_bounds__(256) void gemm_mfma(
    const unsigned short* __restrict__ A,   // [M][256] bf16
    const unsigned short* __restrict__ W,   // per-rel [256][256] bf16
    void* __restrict__ Cout, int relW, long relC, int M)
{
    __shared__ unsigned short sA[128][72];  // 64-k chunk, stride 72 (2-way bank alias = free)
    __shared__ unsigned short sB[128][72];
    const int K = 256;
    int tid = threadIdx.x;
    int wid = tid >> 6, lane = tid & 63;
    int wr = wid >> 1, wc = wid & 1;
    int n0 = blockIdx.x * 128;
    int o0 = blockIdx.y * 128;
    const unsigned short* Wr = W + (size_t)blockIdx.z * relW;

    f32x4 acc[4][4] = {};

    for (int k0 = 0; k0 < K; k0 += 64) {
        #pragma unroll
        for (int p = 0; p < 4; ++p) {
            int flat = p * 256 + tid;            // 0..1023
            int row = flat >> 3, k8 = (flat & 7) * 8;
            int gr = n0 + row;
            short8v va = {0, 0, 0, 0, 0, 0, 0, 0};
            if (gr < M) va = *reinterpret_cast<const short8v*>(A + (size_t)gr * K + k0 + k8);
            *reinterpret_cast<short8v*>(&sA[row][k8]) = va;
            short8v vb = *reinterpret_cast<const short8v*>(Wr + (size_t)(o0 + row) * K + k0 + k8);
            *reinterpret_cast<short8v*>(&sB[row][k8]) = vb;
        }
        __syncthreads();
        #pragma unroll
        for (int kk = 0; kk < 2; ++kk) {
            short8v af[4], bf[4];
            int klo = kk * 32 + (lane >> 4) * 8;
            #pragma unroll
            for (int m = 0; m < 4; ++m)
                af[m] = *reinterpret_cast<const short8v*>(&sA[wr * 64 + m * 16 + (lane & 15)][klo]);
            #pragma unroll
            for (int n = 0; n < 4; ++n)
                bf[n] = *reinterpret_cast<const short8v*>(&sB[wc * 64 + n * 16 + (lane & 15)][klo]);
            #pragma unroll
            for (int m = 0; m < 4; ++m)
                #pragma unroll
                for (int n = 0; n < 4; ++n)
                    acc[m][n] = __builtin_amdgcn_mfma_f32_16x16x32_bf16(af[m], bf[n], acc[m][n], 0, 0, 0);
        }
        __syncthreads();
    }
    int col0 = o0 + wc * 64;
    int rbase = (lane >> 4) * 4;
    #pragma unroll
    for (int m = 0; m < 4; ++m) {
        #pragma unroll
        for (int j = 0; j < 4; ++j) {
            int gr = n0 + wr * 64 + m * 16 + rbase + j;
            if (gr >= M) continue;
            #pragma unroll
            for (int n = 0; n < 4; ++n) {
                int gc = col0 + n * 16 + (lane & 15);
                size_t idx = (size_t)blockIdx.z * relC + (size_t)gr * 256 + gc;
                if constexpr (BF16OUT) ((unsigned short*)Cout)[idx] = f2bf(acc[m][n][j]);
                else                   ((float*)Cout)[idx] = acc[m][n][j];
            }
        }
    }
}

// ---------------- Layer-1 edge softmax + aggregation (H=4, D=64) ----------------
// Persistent waves, STATIC interleaved node assignment (no atomics: R5 lesson —
// a contended counter line serializes at ~14ns/op). 2048x256 grid fills 32 waves/CU.
#define NWAVE1 8192
__global__ __launch_bounds__(256, 8) void agg1_k(
    const unsigned short* __restrict__ feat,   // [2][NN][256] bf16
    const unsigned short* __restrict__ xb,     // [NN][256] bf16 (residual)
    const float* __restrict__ a1,              // [2][256]
    const float* __restrict__ b1,              // [2][256]
    const int* __restrict__ rowptr, const int* __restrict__ csr,
    unsigned short* __restrict__ hb)           // [NN][256] bf16 out
{
    int lane = threadIdx.x & 63;
    int g = __builtin_amdgcn_readfirstlane((blockIdx.x << 2) | (threadIdx.x >> 6));
    unsigned laneoff = (unsigned)lane * 8u;    // byte offset of this lane's 8B in a 512B row
    int c = lane * 4;
    // hoisted lane-only coefficients
    float4 av0v = *reinterpret_cast<const float4*>(a1 + c);
    float4 av1v = *reinterpret_cast<const float4*>(a1 + 256 + c);
    float p6[2][4], q4[2][4];
    p6[0][0] = 0.6f * av0v.x; q4[0][0] = 0.4f * av0v.x;
    p6[0][1] = 0.6f * av0v.y; q4[0][1] = 0.4f * av0v.y;
    p6[0][2] = 0.6f * av0v.z; q4[0][2] = 0.4f * av0v.z;
    p6[0][3] = 0.6f * av0v.w; q4[0][3] = 0.4f * av0v.w;
    p6[1][0] = 0.6f * av1v.x; q4[1][0] = 0.4f * av1v.x;
    p6[1][1] = 0.6f * av1v.y; q4[1][1] = 0.4f * av1v.y;
    p6[1][2] = 0.6f * av1v.z; q4[1][2] = 0.4f * av1v.z;
    p6[1][3] = 0.6f * av1v.w; q4[1][3] = 0.4f * av1v.w;
    float bsum0 = b1[c + 0] + b1[256 + c + 0];
    float bsum1 = b1[c + 1] + b1[256 + c + 1];
    float bsum2 = b1[c + 2] + b1[256 + c + 2];
    float bsum3 = b1[c + 3] + b1[256 + c + 3];

    for (int n = g; n < NN; n += NWAVE1) {
        float t0 = 0.f, t1 = 0.f, t2 = 0.f, t3 = 0.f;
        #pragma unroll
        for (int r = 0; r < 2; ++r) {
            const char* frB = (const char*)(feat + (size_t)r * NN * 256);
            uint2 ud = *reinterpret_cast<const uint2*>(frB + (((unsigned)n << 9) | laneoff));
            float fd0 = bflo(ud.x), fd1 = bfhi(ud.x), fd2 = bflo(ud.y), fd3 = bfhi(ud.y);
            float lsum = 0.f;
            float a0 = 0.f, a1v = 0.f, a2v = 0.f, a3 = 0.f;
            int beg = rowptr[r * (NN + 1) + n], end = rowptr[r * (NN + 1) + n + 1];
            const int* cp = csr + (size_t)r * EE;
            for (int e = beg; e < end; ++e) {
                int s = cp[e];
                uint2 us = *reinterpret_cast<const uint2*>(frB + (((unsigned)s << 9) | laneoff));
                float fs0 = bflo(us.x), fs1 = bfhi(us.x), fs2 = bflo(us.y), fs3 = bfhi(us.y);
                float t, part;
                t = fs0 + fd0; part  = p6[r][0] * t + q4[r][0] * fabsf(t);
                t = fs1 + fd1; part += p6[r][1] * t; part += q4[r][1] * fabsf(t);
                t = fs2 + fd2; part += p6[r][2] * t; part += q4[r][2] * fabsf(t);
                t = fs3 + fd3; part += p6[r][3] * t; part += q4[r][3] * fabsf(t);
                part += __shfl_xor(part, 1);
                part += __shfl_xor(part, 2);
                part += __shfl_xor(part, 4);
                part += __shfl_xor(part, 8);
                float p = __expf(part);
                lsum += p;
                a0  += p * fs0;
                a1v += p * fs1;
                a2v += p * fs2;
                a3  += p * fs3;
            }
            float inv = 1.f / fmaxf(lsum, 1e-16f);
            t0 += a0 * inv; t1 += a1v * inv; t2 += a2v * inv; t3 += a3 * inv;
        }
        unsigned o = ((unsigned)n << 8) + (unsigned)c;
        uint2 xv = *reinterpret_cast<const uint2*>(xb + o);
        float v0 = fmaxf(t0 + 2.f * bflo(xv.x) + bsum0, 0.f);
        float v1 = fmaxf(t1 + 2.f * bfhi(xv.x) + bsum1, 0.f);
        float v2 = fmaxf(t2 + 2.f * bflo(xv.y) + bsum2, 0.f);
        float v3 = fmaxf(t3 + 2.f * bfhi(xv.y) + bsum3, 0.f);
        ushort4 ho;
        ho.x = f2bf(v0); ho.y = f2bf(v1); ho.z = f2bf(v2); ho.w = f2bf(v3);
        reinterpret_cast<ushort4*>(hb)[((unsigned)n << 6) + (unsigned)lane] = ho;
    }
}

// ---------------- Layer-2 helpers ----------------
__global__ void build_wcat_bf(const float* __restrict__ W2, const float* __restrict__ Wres2,
                              unsigned short* __restrict__ Wcat) {
    int i = blockIdx.x * 256 + threadIdx.x;
    if (i >= 256 * 256) return;
    int o = i >> 8, k = i & 255;
    int sel = o >> 6, row = o & 63;
    int r = sel >> 1;
    const float* Wsrc = (sel & 1) ? Wres2 : W2;
    Wcat[i] = f2bf(Wsrc[((size_t)r * 64 + row) * 256 + k]);
}

__global__ void post2(const float* __restrict__ G, const float* __restrict__ b2,
                      unsigned short* __restrict__ feat2, float* __restrict__ base) {
    int i = blockIdx.x * 256 + threadIdx.x;
    if (i >= NN * 64) return;
    int n = i >> 6, d = i & 63;
    const float* g = G + (size_t)n * 256;
    feat2[i] = f2bf(g[d]);
    feat2[(size_t)NN * 64 + i] = f2bf(g[128 + d]);
    base[i] = g[64 + d] + g[192 + d] + b2[d] + b2[64 + d];
}

// ---------------- Layer-2 edge softmax + aggregation (H=1, D=64) ----------------
__global__ __launch_bounds__(256, 8) void agg2_k(
    const unsigned short* __restrict__ feat2,  // [2][NN][64] bf16
    const float* __restrict__ base,
    const float* __restrict__ a2,              // [2][64]
    const int* __restrict__ rowptr, const int* __restrict__ csr,
    float* __restrict__ out)
{
    int lane = threadIdx.x & 63;
    int g = __builtin_amdgcn_readfirstlane((blockIdx.x << 2) | (threadIdx.x >> 6));
    unsigned laneoff = (unsigned)lane * 2u;    // byte offset in 128B row
    float av0 = a2[lane], av1 = a2[64 + lane];
    float p6a[2] = {0.6f * av0, 0.6f * av1};
    float q4a[2] = {0.4f * av0, 0.4f * av1};

    for (int n = g; n < NN; n += NWAVE1) {
        float tot = 0.f;
        #pragma unroll
        for (int r = 0; r < 2; ++r) {
            const char* frB = (const char*)(feat2 + (size_t)r * NN * 64);
            float fd = bf2f(*reinterpret_cast<const unsigned short*>(frB + (((unsigned)n << 7) | laneoff)));
            float lsum = 0.f, acc = 0.f;
            int beg = rowptr[r * (NN + 1) + n], end = rowptr[r * (NN + 1) + n + 1];
            const int* cp = csr + (size_t)r * EE;
            for (int e = beg; e < end; ++e) {
                int s = cp[e];
                float fs = bf2f(*reinterpret_cast<const unsigned short*>(frB + (((unsigned)s << 7) | laneoff)));
                float t = fs + fd;
                float part = p6a[r] * t + q4a[r] * fabsf(t);
                part += __shfl_xor(part, 1);
                part += __shfl_xor(part, 2);
                part += __shfl_xor(part, 4);
                part += __shfl_xor(part, 8);
                part += __shfl_xor(part, 16);
                part += __shfl_xor(part, 32);
                float p = __expf(part);
                lsum += p;
                acc += p * fs;
            }
            tot += acc / fmaxf(lsum, 1e-16f);
        }
        unsigned o = ((unsigned)n << 6) + (unsigned)lane;
        out[o] = fmaxf(tot + base[o], 0.f);
    }
}

extern "C" void kernel_launch(void* const* d_in, const int* in_sizes, int n_in,
                              void* d_out, int out_size, void* d_ws, size_t ws_size,
                              hipStream_t stream) {
    (void)in_sizes; (void)n_in; (void)out_size; (void)ws_size;
    const float* x     = (const float*)d_in[0];
    const int*   src   = (const int*)d_in[1];
    const int*   dst   = (const int*)d_in[2];
    const float* W1    = (const float*)d_in[3];
    const float* a1    = (const float*)d_in[4];
    const float* b1    = (const float*)d_in[5];
    const float* W2    = (const float*)d_in[6];
    const float* a2    = (const float*)d_in[7];
    const float* b2    = (const float*)d_in[8];
    const float* Wres2 = (const float*)d_in[9];
    float* out = (float*)d_out;

    char* w = (char*)d_ws;
    size_t off = 0;
    auto alloc = [&](size_t bytes) -> void* {
        void* p = w + off;
        off = (off + bytes + 255) & ~(size_t)255;
        return p;
    };
    int* cursor = (int*)alloc((size_t)2 * NN * sizeof(int));
    int* rowptr = (int*)alloc((size_t)2 * (NN + 1) * sizeof(int));
    int* csr    = (int*)alloc((size_t)2 * EE * sizeof(int));
    unsigned short* feat1 = (unsigned short*)alloc((size_t)2 * NN * 256 * 2); // aliased as G (fp32 NN*256)
    float* G = (float*)feat1;
    unsigned short* xb = (unsigned short*)alloc((size_t)NN * 256 * 2);
    unsigned short* hb = (unsigned short*)alloc((size_t)NN * 256 * 2);
    unsigned short* W1b = (unsigned short*)alloc((size_t)2 * 256 * 256 * 2);
    unsigned short* Wcatb = (unsigned short*)alloc((size_t)256 * 256 * 2);
    unsigned short* feat2 = (unsigned short*)alloc((size_t)2 * NN * 64 * 2);
    float* base = (float*)alloc((size_t)NN * 64 * 4);

    // conversions
    cvt_f2bf<<<(NN * 256 / 4 + 255) / 256, 256, 0, stream>>>(x, xb, NN * 256 / 4);
    cvt_f2bf<<<(2 * 256 * 256 / 4 + 255) / 256, 256, 0, stream>>>(W1, W1b, 2 * 256 * 256 / 4);
    build_wcat_bf<<<(256 * 256 + 255) / 256, 256, 0, stream>>>(W2, Wres2, Wcatb);

    // CSR
    hipMemsetAsync(cursor, 0, (size_t)2 * NN * sizeof(int), stream);
    count_k<<<(2 * EE + 255) / 256, 256, 0, stream>>>(dst, cursor);
    scan_k<<<2, 1024, 0, stream>>>(cursor, rowptr);
    scatter_k<<<(2 * EE + 255) / 256, 256, 0, stream>>>(src, dst, cursor, csr);

    // Layer 1
    dim3 g1((NN + 127) / 128, 2, 2);
    gemm_mfma<true><<<g1, 256, 0, stream>>>(xb, W1b, feat1, 256 * 256, (long)NN * 256, NN);
    agg1_k<<<2048, 256, 0, stream>>>(feat1, xb, a1, b1, rowptr, csr, hb);

    // Layer 2
    dim3 g2((NN + 127) / 128, 2, 1);
    gemm_mfma<false><<<g2, 256, 0, stream>>>(hb, Wcatb, G, 0, 0, NN);
    post2<<<(NN * 64 + 255) / 256, 256, 0, stream>>>(G, b2, feat2, base);
    agg2_k<<<2048, 256, 0, stream>>>(feat2, base, a2, rowptr, csr, out);
}

// Round 7
// 616.013 us; speedup vs baseline: 2.8966x; 1.1114x over previous
//
#include <hip/hip_runtime.h>
#include <hip/hip_bf16.h>

#define NN 50000
#define EE 800000

typedef __attribute__((ext_vector_type(8))) short short8v;
typedef __attribute__((ext_vector_type(4))) float f32x4;

__device__ __forceinline__ float bf2f(unsigned short u) {
    return __uint_as_float(((unsigned int)u) << 16);
}
__device__ __forceinline__ float bflo(unsigned int u) {
    return __uint_as_float(u << 16);
}
__device__ __forceinline__ float bfhi(unsigned int u) {
    return __uint_as_float(u & 0xffff0000u);
}
__device__ __forceinline__ unsigned short f2bf(float f) {
    unsigned int u = __float_as_uint(f);
    unsigned int r = 0x7FFF + ((u >> 16) & 1);
    return (unsigned short)((u + r) >> 16);
}

// ---------------- fp32 -> bf16 conversion (vectorized) ----------------
__global__ void cvt_f2bf(const float* __restrict__ in, unsigned short* __restrict__ out, int n4) {
    int i = blockIdx.x * 256 + threadIdx.x;
    if (i >= n4) return;
    float4 v = reinterpret_cast<const float4*>(in)[i];
    ushort4 o;
    o.x = f2bf(v.x); o.y = f2bf(v.y); o.z = f2bf(v.z); o.w = f2bf(v.w);
    reinterpret_cast<ushort4*>(out)[i] = o;
}

// ---------------- CSR construction ----------------
__global__ void count_k(const int* __restrict__ dst, int* __restrict__ cursor) {
    int i = blockIdx.x * 256 + threadIdx.x;
    if (i >= 2 * EE) return;
    int r = (i >= EE) ? 1 : 0;
    atomicAdd(&cursor[r * NN + dst[i]], 1);
}

__global__ __launch_bounds__(1024) void scan_k(int* __restrict__ cursor, int* __restrict__ rowptr) {
    int r = blockIdx.x;
    int* cnt = cursor + r * NN;          // counts in, exclusive prefix out
    int* rp  = rowptr + r * (NN + 1);
    int tid = threadIdx.x;
    const int CH = (NN + 1023) / 1024;   // 49
    int beg = tid * CH;
    int end = beg + CH; if (end > NN) end = NN;
    int s = 0;
    for (int i = beg; i < end && i < NN; ++i) s += cnt[i];
    __shared__ int sums[1024];
    sums[tid] = s;
    __syncthreads();
    for (int offd = 1; offd < 1024; offd <<= 1) {
        int v = 0;
        if (tid >= offd) v = sums[tid - offd];
        __syncthreads();
        sums[tid] += v;
        __syncthreads();
    }
    int run = sums[tid] - s;             // exclusive offset for this chunk
    for (int i = beg; i < end && i < NN; ++i) {
        int c = cnt[i];
        rp[i] = run;
        cnt[i] = run;                    // cursor for scatter
        run += c;
    }
    if (tid == 1023) rp[NN] = sums[1023];
}

__global__ void scatter_k(const int* __restrict__ src, const int* __restrict__ dst,
                          int* __restrict__ cursor, int* __restrict__ csr) {
    int i = blockIdx.x * 256 + threadIdx.x;
    if (i >= 2 * EE) return;
    int r = (i >= EE) ? 1 : 0;
    int pos = atomicAdd(&cursor[r * NN + dst[i]], 1);
    csr[r * EE + pos] = src[i];
}

// ---------------- MFMA GEMM: C[n,o] = sum_k A[n,k]*W[o,k]; A,W bf16; K=256 ----------------
template<bool BF16OUT>
__global__ __launch_bounds__(256) void gemm_mfma(
    const unsigned short* __restrict__ A,   // [M][256] bf16
    const unsigned short* __restrict__ W,   // per-rel [256][256] bf16
    void* __restrict__ Cout, int relW, long relC, int M)
{
    __shared__ unsigned short sA[128][72];  // 64-k chunk, stride 72 (2-way bank alias = free)
    __shared__ unsigned short sB[128][72];
    const int K = 256;
    int tid = threadIdx.x;
    int wid = tid >> 6, lane = tid & 63;
    int wr = wid >> 1, wc = wid & 1;
    int n0 = blockIdx.x * 128;
    int o0 = blockIdx.y * 128;
    const unsigned short* Wr = W + (size_t)blockIdx.z * relW;

    f32x4 acc[4][4] = {};

    for (int k0 = 0; k0 < K; k0 += 64) {
        #pragma unroll
        for (int p = 0; p < 4; ++p) {
            int flat = p * 256 + tid;            // 0..1023
            int row = flat >> 3, k8 = (flat & 7) * 8;
            int gr = n0 + row;
            short8v va = {0, 0, 0, 0, 0, 0, 0, 0};
            if (gr < M) va = *reinterpret_cast<const short8v*>(A + (size_t)gr * K + k0 + k8);
            *reinterpret_cast<short8v*>(&sA[row][k8]) = va;
            short8v vb = *reinterpret_cast<const short8v*>(Wr + (size_t)(o0 + row) * K + k0 + k8);
            *reinterpret_cast<short8v*>(&sB[row][k8]) = vb;
        }
        __syncthreads();
        #pragma unroll
        for (int kk = 0; kk < 2; ++kk) {
            short8v af[4], bf[4];
            int klo = kk * 32 + (lane >> 4) * 8;
            #pragma unroll
            for (int m = 0; m < 4; ++m)
                af[m] = *reinterpret_cast<const short8v*>(&sA[wr * 64 + m * 16 + (lane & 15)][klo]);
            #pragma unroll
            for (int n = 0; n < 4; ++n)
                bf[n] = *reinterpret_cast<const short8v*>(&sB[wc * 64 + n * 16 + (lane & 15)][klo]);
            #pragma unroll
            for (int m = 0; m < 4; ++m)
                #pragma unroll
                for (int n = 0; n < 4; ++n)
                    acc[m][n] = __builtin_amdgcn_mfma_f32_16x16x32_bf16(af[m], bf[n], acc[m][n], 0, 0, 0);
        }
        __syncthreads();
    }
    int col0 = o0 + wc * 64;
    int rbase = (lane >> 4) * 4;
    #pragma unroll
    for (int m = 0; m < 4; ++m) {
        #pragma unroll
        for (int j = 0; j < 4; ++j) {
            int gr = n0 + wr * 64 + m * 16 + rbase + j;
            if (gr >= M) continue;
            #pragma unroll
            for (int n = 0; n < 4; ++n) {
                int gc = col0 + n * 16 + (lane & 15);
                size_t idx = (size_t)blockIdx.z * relC + (size_t)gr * 256 + gc;
                if constexpr (BF16OUT) ((unsigned short*)Cout)[idx] = f2bf(acc[m][n][j]);
                else                   ((float*)Cout)[idx] = acc[m][n][j];
            }
        }
    }
}

// ---------------- Layer-1 edge softmax + aggregation (H=4, D=64) ----------------
// 1 wave per node (R4 structure, self-balancing retirement) + 2-edge ILP:
// both row gathers issue before any compute -> 2 outstanding L2/L3 misses per wave.
__global__ __launch_bounds__(64) void agg1_k(
    const unsigned short* __restrict__ feat,   // [2][NN][256] bf16
    const unsigned short* __restrict__ xb,     // [NN][256] bf16 (residual)
    const float* __restrict__ a1,              // [2][256]
    const float* __restrict__ b1,              // [2][256]
    const int* __restrict__ rowptr, const int* __restrict__ csr,
    unsigned short* __restrict__ hb)           // [NN][256] bf16 out
{
    int n = blockIdx.x, lane = threadIdx.x;
    unsigned laneoff = (unsigned)lane * 8u;    // byte offset of this lane's 8B in a 512B row
    int c = lane * 4;
    float4 av0v = *reinterpret_cast<const float4*>(a1 + c);
    float4 av1v = *reinterpret_cast<const float4*>(a1 + 256 + c);
    float p6[2][4], q4[2][4];
    p6[0][0] = 0.6f * av0v.x; q4[0][0] = 0.4f * av0v.x;
    p6[0][1] = 0.6f * av0v.y; q4[0][1] = 0.4f * av0v.y;
    p6[0][2] = 0.6f * av0v.z; q4[0][2] = 0.4f * av0v.z;
    p6[0][3] = 0.6f * av0v.w; q4[0][3] = 0.4f * av0v.w;
    p6[1][0] = 0.6f * av1v.x; q4[1][0] = 0.4f * av1v.x;
    p6[1][1] = 0.6f * av1v.y; q4[1][1] = 0.4f * av1v.y;
    p6[1][2] = 0.6f * av1v.z; q4[1][2] = 0.4f * av1v.z;
    p6[1][3] = 0.6f * av1v.w; q4[1][3] = 0.4f * av1v.w;
    float bsum0 = b1[c + 0] + b1[256 + c + 0];
    float bsum1 = b1[c + 1] + b1[256 + c + 1];
    float bsum2 = b1[c + 2] + b1[256 + c + 2];
    float bsum3 = b1[c + 3] + b1[256 + c + 3];

    float t0 = 0.f, t1 = 0.f, t2 = 0.f, t3 = 0.f;
    #pragma unroll
    for (int r = 0; r < 2; ++r) {
        const char* frB = (const char*)(feat + (size_t)r * NN * 256);
        uint2 ud = *reinterpret_cast<const uint2*>(frB + (((unsigned)n << 9) | laneoff));
        float fd0 = bflo(ud.x), fd1 = bfhi(ud.x), fd2 = bflo(ud.y), fd3 = bfhi(ud.y);
        float lsum = 0.f;
        float a0 = 0.f, a1v = 0.f, a2v = 0.f, a3 = 0.f;
        int beg = rowptr[r * (NN + 1) + n], end = rowptr[r * (NN + 1) + n + 1];
        const int* cp = csr + (size_t)r * EE;
        int e = beg;
        for (; e + 2 <= end; e += 2) {
            int s0 = cp[e], s1 = cp[e + 1];
            uint2 u0 = *reinterpret_cast<const uint2*>(frB + (((unsigned)s0 << 9) | laneoff));
            uint2 u1 = *reinterpret_cast<const uint2*>(frB + (((unsigned)s1 << 9) | laneoff));
            float f00 = bflo(u0.x), f01 = bfhi(u0.x), f02 = bflo(u0.y), f03 = bfhi(u0.y);
            float f10 = bflo(u1.x), f11 = bfhi(u1.x), f12 = bflo(u1.y), f13 = bfhi(u1.y);
            float t, part0, part1;
            t = f00 + fd0; part0  = p6[r][0] * t + q4[r][0] * fabsf(t);
            t = f01 + fd1; part0 += p6[r][1] * t; part0 += q4[r][1] * fabsf(t);
            t = f02 + fd2; part0 += p6[r][2] * t; part0 += q4[r][2] * fabsf(t);
            t = f03 + fd3; part0 += p6[r][3] * t; part0 += q4[r][3] * fabsf(t);
            t = f10 + fd0; part1  = p6[r][0] * t + q4[r][0] * fabsf(t);
            t = f11 + fd1; part1 += p6[r][1] * t; part1 += q4[r][1] * fabsf(t);
            t = f12 + fd2; part1 += p6[r][2] * t; part1 += q4[r][2] * fabsf(t);
            t = f13 + fd3; part1 += p6[r][3] * t; part1 += q4[r][3] * fabsf(t);
            part0 += __shfl_xor(part0, 1); part1 += __shfl_xor(part1, 1);
            part0 += __shfl_xor(part0, 2); part1 += __shfl_xor(part1, 2);
            part0 += __shfl_xor(part0, 4); part1 += __shfl_xor(part1, 4);
            part0 += __shfl_xor(part0, 8); part1 += __shfl_xor(part1, 8);
            float p0 = __expf(part0), p1 = __expf(part1);
            lsum += p0 + p1;
            a0  += p0 * f00; a1v += p0 * f01; a2v += p0 * f02; a3  += p0 * f03;
            a0  += p1 * f10; a1v += p1 * f11; a2v += p1 * f12; a3  += p1 * f13;
        }
        if (e < end) {
            int s = cp[e];
            uint2 us = *reinterpret_cast<const uint2*>(frB + (((unsigned)s << 9) | laneoff));
            float fs0 = bflo(us.x), fs1 = bfhi(us.x), fs2 = bflo(us.y), fs3 = bfhi(us.y);
            float t, part;
            t = fs0 + fd0; part  = p6[r][0] * t + q4[r][0] * fabsf(t);
            t = fs1 + fd1; part += p6[r][1] * t; part += q4[r][1] * fabsf(t);
            t = fs2 + fd2; part += p6[r][2] * t; part += q4[r][2] * fabsf(t);
            t = fs3 + fd3; part += p6[r][3] * t; part += q4[r][3] * fabsf(t);
            part += __shfl_xor(part, 1);
            part += __shfl_xor(part, 2);
            part += __shfl_xor(part, 4);
            part += __shfl_xor(part, 8);
            float p = __expf(part);
            lsum += p;
            a0  += p * fs0; a1v += p * fs1; a2v += p * fs2; a3  += p * fs3;
        }
        float inv = 1.f / fmaxf(lsum, 1e-16f);
        t0 += a0 * inv; t1 += a1v * inv; t2 += a2v * inv; t3 += a3 * inv;
    }
    unsigned o = ((unsigned)n << 8) + (unsigned)c;
    uint2 xv = *reinterpret_cast<const uint2*>(xb + o);
    float v0 = fmaxf(t0 + 2.f * bflo(xv.x) + bsum0, 0.f);
    float v1 = fmaxf(t1 + 2.f * bfhi(xv.x) + bsum1, 0.f);
    float v2 = fmaxf(t2 + 2.f * bflo(xv.y) + bsum2, 0.f);
    float v3 = fmaxf(t3 + 2.f * bfhi(xv.y) + bsum3, 0.f);
    ushort4 ho;
    ho.x = f2bf(v0); ho.y = f2bf(v1); ho.z = f2bf(v2); ho.w = f2bf(v3);
    reinterpret_cast<ushort4*>(hb)[((unsigned)n << 6) + (unsigned)lane] = ho;
}

// ---------------- Layer-2 helpers ----------------
__global__ void build_wcat_bf(const float* __restrict__ W2, const float* __restrict__ Wres2,
                              unsigned short* __restrict__ Wcat) {
    int i = blockIdx.x * 256 + threadIdx.x;
    if (i >= 256 * 256) return;
    int o = i >> 8, k = i & 255;
    int sel = o >> 6, row = o & 63;
    int r = sel >> 1;
    const float* Wsrc = (sel & 1) ? Wres2 : W2;
    Wcat[i] = f2bf(Wsrc[((size_t)r * 64 + row) * 256 + k]);
}

__global__ void post2(const float* __restrict__ G, const float* __restrict__ b2,
                      unsigned short* __restrict__ feat2, float* __restrict__ base) {
    int i = blockIdx.x * 256 + threadIdx.x;
    if (i >= NN * 64) return;
    int n = i >> 6, d = i & 63;
    const float* g = G + (size_t)n * 256;
    feat2[i] = f2bf(g[d]);
    feat2[(size_t)NN * 64 + i] = f2bf(g[128 + d]);
    base[i] = g[64 + d] + g[192 + d] + b2[d] + b2[64 + d];
}

// ---------------- Layer-2 edge softmax + aggregation (H=1, D=64) ----------------
__global__ __launch_bounds__(64) void agg2_k(
    const unsigned short* __restrict__ feat2,  // [2][NN][64] bf16
    const float* __restrict__ base,
    const float* __restrict__ a2,              // [2][64]
    const int* __restrict__ rowptr, const int* __restrict__ csr,
    float* __restrict__ out)
{
    int n = blockIdx.x, lane = threadIdx.x;
    unsigned laneoff = (unsigned)lane * 2u;    // byte offset in 128B row
    float av0 = a2[lane], av1 = a2[64 + lane];
    float p6a[2] = {0.6f * av0, 0.6f * av1};
    float q4a[2] = {0.4f * av0, 0.4f * av1};

    float tot = 0.f;
    #pragma unroll
    for (int r = 0; r < 2; ++r) {
        const char* frB = (const char*)(feat2 + (size_t)r * NN * 64);
        float fd = bf2f(*reinterpret_cast<const unsigned short*>(frB + (((unsigned)n << 7) | laneoff)));
        float lsum = 0.f, acc = 0.f;
        int beg = rowptr[r * (NN + 1) + n], end = rowptr[r * (NN + 1) + n + 1];
        const int* cp = csr + (size_t)r * EE;
        int e = beg;
        for (; e + 2 <= end; e += 2) {
            int s0 = cp[e], s1 = cp[e + 1];
            float fs0 = bf2f(*reinterpret_cast<const unsigned short*>(frB + (((unsigned)s0 << 7) | laneoff)));
            float fs1 = bf2f(*reinterpret_cast<const unsigned short*>(frB + (((unsigned)s1 << 7) | laneoff)));
            float ta = fs0 + fd, tb = fs1 + fd;
            float part0 = p6a[r] * ta + q4a[r] * fabsf(ta);
            float part1 = p6a[r] * tb + q4a[r] * fabsf(tb);
            part0 += __shfl_xor(part0, 1);  part1 += __shfl_xor(part1, 1);
            part0 += __shfl_xor(part0, 2);  part1 += __shfl_xor(part1, 2);
            part0 += __shfl_xor(part0, 4);  part1 += __shfl_xor(part1, 4);
            part0 += __shfl_xor(part0, 8);  part1 += __shfl_xor(part1, 8);
            part0 += __shfl_xor(part0, 16); part1 += __shfl_xor(part1, 16);
            part0 += __shfl_xor(part0, 32); part1 += __shfl_xor(part1, 32);
            float p0 = __expf(part0), p1 = __expf(part1);
            lsum += p0 + p1;
            acc += p0 * fs0;
            acc += p1 * fs1;
        }
        if (e < end) {
            int s = cp[e];
            float fs = bf2f(*reinterpret_cast<const unsigned short*>(frB + (((unsigned)s << 7) | laneoff)));
            float t = fs + fd;
            float part = p6a[r] * t + q4a[r] * fabsf(t);
            part += __shfl_xor(part, 1);
            part += __shfl_xor(part, 2);
            part += __shfl_xor(part, 4);
            part += __shfl_xor(part, 8);
            part += __shfl_xor(part, 16);
            part += __shfl_xor(part, 32);
            float p = __expf(part);
            lsum += p;
            acc += p * fs;
        }
        tot += acc / fmaxf(lsum, 1e-16f);
    }
    unsigned o = ((unsigned)n << 6) + (unsigned)lane;
    out[o] = fmaxf(tot + base[o], 0.f);
}

extern "C" void kernel_launch(void* const* d_in, const int* in_sizes, int n_in,
                              void* d_out, int out_size, void* d_ws, size_t ws_size,
                              hipStream_t stream) {
    (void)in_sizes; (void)n_in; (void)out_size; (void)ws_size;
    const float* x     = (const float*)d_in[0];
    const int*   src   = (const int*)d_in[1];
    const int*   dst   = (const int*)d_in[2];
    const float* W1    = (const float*)d_in[3];
    const float* a1    = (const float*)d_in[4];
    const float* b1    = (const float*)d_in[5];
    const float* W2    = (const float*)d_in[6];
    const float* a2    = (const float*)d_in[7];
    const float* b2    = (const float*)d_in[8];
    const float* Wres2 = (const float*)d_in[9];
    float* out = (float*)d_out;

    char* w = (char*)d_ws;
    size_t off = 0;
    auto alloc = [&](size_t bytes) -> void* {
        void* p = w + off;
        off = (off + bytes + 255) & ~(size_t)255;
        return p;
    };
    int* cursor = (int*)alloc((size_t)2 * NN * sizeof(int));
    int* rowptr = (int*)alloc((size_t)2 * (NN + 1) * sizeof(int));
    int* csr    = (int*)alloc((size_t)2 * EE * sizeof(int));
    unsigned short* feat1 = (unsigned short*)alloc((size_t)2 * NN * 256 * 2); // aliased as G (fp32 NN*256)
    float* G = (float*)feat1;
    unsigned short* xb = (unsigned short*)alloc((size_t)NN * 256 * 2);
    unsigned short* hb = (unsigned short*)alloc((size_t)NN * 256 * 2);
    unsigned short* W1b = (unsigned short*)alloc((size_t)2 * 256 * 256 * 2);
    unsigned short* Wcatb = (unsigned short*)alloc((size_t)256 * 256 * 2);
    unsigned short* feat2 = (unsigned short*)alloc((size_t)2 * NN * 64 * 2);
    float* base = (float*)alloc((size_t)NN * 64 * 4);

    // conversions
    cvt_f2bf<<<(NN * 256 / 4 + 255) / 256, 256, 0, stream>>>(x, xb, NN * 256 / 4);
    cvt_f2bf<<<(2 * 256 * 256 / 4 + 255) / 256, 256, 0, stream>>>(W1, W1b, 2 * 256 * 256 / 4);
    build_wcat_bf<<<(256 * 256 + 255) / 256, 256, 0, stream>>>(W2, Wres2, Wcatb);

    // CSR
    hipMemsetAsync(cursor, 0, (size_t)2 * NN * sizeof(int), stream);
    count_k<<<(2 * EE + 255) / 256, 256, 0, stream>>>(dst, cursor);
    scan_k<<<2, 1024, 0, stream>>>(cursor, rowptr);
    scatter_k<<<(2 * EE + 255) / 256, 256, 0, stream>>>(src, dst, cursor, csr);

    // Layer 1
    dim3 g1((NN + 127) / 128, 2, 2);
    gemm_mfma<true><<<g1, 256, 0, stream>>>(xb, W1b, feat1, 256 * 256, (long)NN * 256, NN);
    agg1_k<<<NN, 64, 0, stream>>>(feat1, xb, a1, b1, rowptr, csr, hb);

    // Layer 2
    dim3 g2((NN + 127) / 128, 2, 1);
    gemm_mfma<false><<<g2, 256, 0, stream>>>(hb, Wcatb, G, 0, 0, NN);
    post2<<<(NN * 64 + 255) / 256, 256, 0, stream>>>(G, b2, feat2, base);
    agg2_k<<<NN, 64, 0, stream>>>(feat2, base, a2, rowptr, csr, out);
}

// Round 8
// 487.035 us; speedup vs baseline: 3.6637x; 1.2648x over previous
//
#include <hip/hip_runtime.h>
#include <hip/hip_bf16.h>

#define NN 50000
#define EE 800000
#define G1BLK 1564   // 391 * 2 * 2 gemm blocks in fused kernel
#define RNKBLK 6250  // ceil(2*EE/256)

typedef __attribute__((ext_vector_type(8))) short short8v;
typedef __attribute__((ext_vector_type(4))) float f32x4;

__device__ __forceinline__ float bf2f(unsigned short u) {
    return __uint_as_float(((unsigned int)u) << 16);
}
__device__ __forceinline__ float bflo(unsigned int u) {
    return __uint_as_float(u << 16);
}
__device__ __forceinline__ float bfhi(unsigned int u) {
    return __uint_as_float(u & 0xffff0000u);
}
__device__ __forceinline__ unsigned short f2bf(float f) {
    unsigned int u = __float_as_uint(f);
    unsigned int r = 0x7FFF + ((u >> 16) & 1);
    return (unsigned short)((u + r) >> 16);
}

// ---------------- fp32 -> bf16 conversion (vectorized) ----------------
__global__ void cvt_f2bf(const float* __restrict__ in, unsigned short* __restrict__ out, int n4) {
    int i = blockIdx.x * 256 + threadIdx.x;
    if (i >= n4) return;
    float4 v = reinterpret_cast<const float4*>(in)[i];
    ushort4 o;
    o.x = f2bf(v.x); o.y = f2bf(v.y); o.z = f2bf(v.z); o.w = f2bf(v.w);
    reinterpret_cast<ushort4*>(out)[i] = o;
}

// ---------------- CSR: scan of counts -> rowptr ----------------
__global__ __launch_bounds__(1024) void scan_k(int* __restrict__ cursor, int* __restrict__ rowptr) {
    int r = blockIdx.x;
    int* cnt = cursor + r * NN;          // counts in (from rank pass)
    int* rp  = rowptr + r * (NN + 1);
    int tid = threadIdx.x;
    const int CH = (NN + 1023) / 1024;   // 49
    int beg = tid * CH;
    int end = beg + CH; if (end > NN) end = NN;
    int s = 0;
    for (int i = beg; i < end && i < NN; ++i) s += cnt[i];
    __shared__ int sums[1024];
    sums[tid] = s;
    __syncthreads();
    for (int offd = 1; offd < 1024; offd <<= 1) {
        int v = 0;
        if (tid >= offd) v = sums[tid - offd];
        __syncthreads();
        sums[tid] += v;
        __syncthreads();
    }
    int run = sums[tid] - s;             // exclusive offset for this chunk
    for (int i = beg; i < end && i < NN; ++i) {
        int c = cnt[i];
        rp[i] = run;
        run += c;
    }
    if (tid == 1023) rp[NN] = sums[1023];
}

// place: no atomics — csr[rowptr[dst]+rank] = src
__global__ void place_k(const int* __restrict__ src, const int* __restrict__ dst,
                        const int* __restrict__ rank, const int* __restrict__ rowptr,
                        int* __restrict__ csr) {
    int i = blockIdx.x * 256 + threadIdx.x;
    if (i >= 2 * EE) return;
    int r = (i >= EE) ? 1 : 0;
    int d = dst[i];
    int pos = rowptr[r * (NN + 1) + d] + rank[i];
    csr[r * EE + pos] = src[i];
}

// ---------------- Fused: layer-1 MFMA GEMM blocks + edge-rank blocks ----------------
// GEMM: C[n,o] = sum_k A[n,k]*W[o,k]; A,W bf16; K=256; tile 128x128.
// Rank: rank[e] = atomicAdd(&cursor[r*NN+dst[e]], 1)  (the single expensive
// atomic pass, co-scheduled with the GEMM: different HW pipes).
__global__ __launch_bounds__(256) void gemm1_rank_k(
    const unsigned short* __restrict__ A,   // [NN][256] bf16
    const unsigned short* __restrict__ W,   // [2][256][256] bf16
    unsigned short* __restrict__ Cout,      // [2][NN][256] bf16
    const int* __restrict__ dst, int* __restrict__ cursor, int* __restrict__ rank)
{
    __shared__ unsigned short sA[128][72];
    __shared__ unsigned short sB[128][72];
    int bid = blockIdx.x;
    int tid = threadIdx.x;
    if (bid >= G1BLK) {
        int i = (bid - G1BLK) * 256 + tid;
        if (i < 2 * EE) {
            int r = (i >= EE) ? 1 : 0;
            rank[i] = atomicAdd(&cursor[r * NN + dst[i]], 1);
        }
        return;
    }
    const int K = 256;
    int bx = bid % 391, by = (bid / 391) & 1, bz = bid / 782;
    int wid = tid >> 6, lane = tid & 63;
    int wr = wid >> 1, wc = wid & 1;
    int n0 = bx * 128;
    int o0 = by * 128;
    const unsigned short* Wr = W + (size_t)bz * 256 * 256;

    f32x4 acc[4][4] = {};

    for (int k0 = 0; k0 < K; k0 += 64) {
        #pragma unroll
        for (int p = 0; p < 4; ++p) {
            int flat = p * 256 + tid;
            int row = flat >> 3, k8 = (flat & 7) * 8;
            int gr = n0 + row;
            short8v va = {0, 0, 0, 0, 0, 0, 0, 0};
            if (gr < NN) va = *reinterpret_cast<const short8v*>(A + (size_t)gr * K + k0 + k8);
            *reinterpret_cast<short8v*>(&sA[row][k8]) = va;
            short8v vb = *reinterpret_cast<const short8v*>(Wr + (size_t)(o0 + row) * K + k0 + k8);
            *reinterpret_cast<short8v*>(&sB[row][k8]) = vb;
        }
        __syncthreads();
        #pragma unroll
        for (int kk = 0; kk < 2; ++kk) {
            short8v af[4], bf[4];
            int klo = kk * 32 + (lane >> 4) * 8;
            #pragma unroll
            for (int m = 0; m < 4; ++m)
                af[m] = *reinterpret_cast<const short8v*>(&sA[wr * 64 + m * 16 + (lane & 15)][klo]);
            #pragma unroll
            for (int n = 0; n < 4; ++n)
                bf[n] = *reinterpret_cast<const short8v*>(&sB[wc * 64 + n * 16 + (lane & 15)][klo]);
            #pragma unroll
            for (int m = 0; m < 4; ++m)
                #pragma unroll
                for (int n = 0; n < 4; ++n)
                    acc[m][n] = __builtin_amdgcn_mfma_f32_16x16x32_bf16(af[m], bf[n], acc[m][n], 0, 0, 0);
        }
        __syncthreads();
    }
    int col0 = o0 + wc * 64;
    int rbase = (lane >> 4) * 4;
    #pragma unroll
    for (int m = 0; m < 4; ++m) {
        #pragma unroll
        for (int j = 0; j < 4; ++j) {
            int gr = n0 + wr * 64 + m * 16 + rbase + j;
            if (gr >= NN) continue;
            #pragma unroll
            for (int n = 0; n < 4; ++n) {
                int gc = col0 + n * 16 + (lane & 15);
                size_t idx = (size_t)bz * NN * 256 + (size_t)gr * 256 + gc;
                Cout[idx] = f2bf(acc[m][n][j]);
            }
        }
    }
}

// ---------------- Layer-2 GEMM (fp32 out), standalone ----------------
__global__ __launch_bounds__(256) void gemm2_k(
    const unsigned short* __restrict__ A,   // [NN][256] bf16
    const unsigned short* __restrict__ W,   // [256][256] bf16
    float* __restrict__ Cout)
{
    __shared__ unsigned short sA[128][72];
    __shared__ unsigned short sB[128][72];
    const int K = 256;
    int tid = threadIdx.x;
    int wid = tid >> 6, lane = tid & 63;
    int wr = wid >> 1, wc = wid & 1;
    int n0 = blockIdx.x * 128;
    int o0 = blockIdx.y * 128;

    f32x4 acc[4][4] = {};

    for (int k0 = 0; k0 < K; k0 += 64) {
        #pragma unroll
        for (int p = 0; p < 4; ++p) {
            int flat = p * 256 + tid;
            int row = flat >> 3, k8 = (flat & 7) * 8;
            int gr = n0 + row;
            short8v va = {0, 0, 0, 0, 0, 0, 0, 0};
            if (gr < NN) va = *reinterpret_cast<const short8v*>(A + (size_t)gr * K + k0 + k8);
            *reinterpret_cast<short8v*>(&sA[row][k8]) = va;
            short8v vb = *reinterpret_cast<const short8v*>(W + (size_t)(o0 + row) * K + k0 + k8);
            *reinterpret_cast<short8v*>(&sB[row][k8]) = vb;
        }
        __syncthreads();
        #pragma unroll
        for (int kk = 0; kk < 2; ++kk) {
            short8v af[4], bf[4];
            int klo = kk * 32 + (lane >> 4) * 8;
            #pragma unroll
            for (int m = 0; m < 4; ++m)
                af[m] = *reinterpret_cast<const short8v*>(&sA[wr * 64 + m * 16 + (lane & 15)][klo]);
            #pragma unroll
            for (int n = 0; n < 4; ++n)
                bf[n] = *reinterpret_cast<const short8v*>(&sB[wc * 64 + n * 16 + (lane & 15)][klo]);
            #pragma unroll
            for (int m = 0; m < 4; ++m)
                #pragma unroll
                for (int n = 0; n < 4; ++n)
                    acc[m][n] = __builtin_amdgcn_mfma_f32_16x16x32_bf16(af[m], bf[n], acc[m][n], 0, 0, 0);
        }
        __syncthreads();
    }
    int col0 = o0 + wc * 64;
    int rbase = (lane >> 4) * 4;
    #pragma unroll
    for (int m = 0; m < 4; ++m) {
        #pragma unroll
        for (int j = 0; j < 4; ++j) {
            int gr = n0 + wr * 64 + m * 16 + rbase + j;
            if (gr >= NN) continue;
            #pragma unroll
            for (int n = 0; n < 4; ++n) {
                int gc = col0 + n * 16 + (lane & 15);
                Cout[(size_t)gr * 256 + gc] = acc[m][n][j];
            }
        }
    }
}

// ---------------- Layer-1 edge softmax + aggregation (H=4, D=64) ----------------
__global__ __launch_bounds__(64) void agg1_k(
    const unsigned short* __restrict__ feat,   // [2][NN][256] bf16
    const unsigned short* __restrict__ xb,     // [NN][256] bf16 (residual)
    const float* __restrict__ a1,              // [2][256]
    const float* __restrict__ b1,              // [2][256]
    const int* __restrict__ rowptr, const int* __restrict__ csr,
    unsigned short* __restrict__ hb)           // [NN][256] bf16 out
{
    int n = blockIdx.x, lane = threadIdx.x;
    unsigned laneoff = (unsigned)lane * 8u;
    int c = lane * 4;
    float4 av0v = *reinterpret_cast<const float4*>(a1 + c);
    float4 av1v = *reinterpret_cast<const float4*>(a1 + 256 + c);
    float p6[2][4], q4[2][4];
    p6[0][0] = 0.6f * av0v.x; q4[0][0] = 0.4f * av0v.x;
    p6[0][1] = 0.6f * av0v.y; q4[0][1] = 0.4f * av0v.y;
    p6[0][2] = 0.6f * av0v.z; q4[0][2] = 0.4f * av0v.z;
    p6[0][3] = 0.6f * av0v.w; q4[0][3] = 0.4f * av0v.w;
    p6[1][0] = 0.6f * av1v.x; q4[1][0] = 0.4f * av1v.x;
    p6[1][1] = 0.6f * av1v.y; q4[1][1] = 0.4f * av1v.y;
    p6[1][2] = 0.6f * av1v.z; q4[1][2] = 0.4f * av1v.z;
    p6[1][3] = 0.6f * av1v.w; q4[1][3] = 0.4f * av1v.w;
    float bsum0 = b1[c + 0] + b1[256 + c + 0];
    float bsum1 = b1[c + 1] + b1[256 + c + 1];
    float bsum2 = b1[c + 2] + b1[256 + c + 2];
    float bsum3 = b1[c + 3] + b1[256 + c + 3];

    float t0 = 0.f, t1 = 0.f, t2 = 0.f, t3 = 0.f;
    #pragma unroll
    for (int r = 0; r < 2; ++r) {
        const char* frB = (const char*)(feat + (size_t)r * NN * 256);
        uint2 ud = *reinterpret_cast<const uint2*>(frB + (((unsigned)n << 9) | laneoff));
        float fd0 = bflo(ud.x), fd1 = bfhi(ud.x), fd2 = bflo(ud.y), fd3 = bfhi(ud.y);
        float lsum = 0.f;
        float a0 = 0.f, a1v = 0.f, a2v = 0.f, a3 = 0.f;
        int beg = rowptr[r * (NN + 1) + n], end = rowptr[r * (NN + 1) + n + 1];
        const int* cp = csr + (size_t)r * EE;
        int e = beg;
        for (; e + 2 <= end; e += 2) {
            int s0 = cp[e], s1 = cp[e + 1];
            uint2 u0 = *reinterpret_cast<const uint2*>(frB + (((unsigned)s0 << 9) | laneoff));
            uint2 u1 = *reinterpret_cast<const uint2*>(frB + (((unsigned)s1 << 9) | laneoff));
            float f00 = bflo(u0.x), f01 = bfhi(u0.x), f02 = bflo(u0.y), f03 = bfhi(u0.y);
            float f10 = bflo(u1.x), f11 = bfhi(u1.x), f12 = bflo(u1.y), f13 = bfhi(u1.y);
            float t, part0, part1;
            t = f00 + fd0; part0  = p6[r][0] * t + q4[r][0] * fabsf(t);
            t = f01 + fd1; part0 += p6[r][1] * t; part0 += q4[r][1] * fabsf(t);
            t = f02 + fd2; part0 += p6[r][2] * t; part0 += q4[r][2] * fabsf(t);
            t = f03 + fd3; part0 += p6[r][3] * t; part0 += q4[r][3] * fabsf(t);
            t = f10 + fd0; part1  = p6[r][0] * t + q4[r][0] * fabsf(t);
            t = f11 + fd1; part1 += p6[r][1] * t; part1 += q4[r][1] * fabsf(t);
            t = f12 + fd2; part1 += p6[r][2] * t; part1 += q4[r][2] * fabsf(t);
            t = f13 + fd3; part1 += p6[r][3] * t; part1 += q4[r][3] * fabsf(t);
            part0 += __shfl_xor(part0, 1); part1 += __shfl_xor(part1, 1);
            part0 += __shfl_xor(part0, 2); part1 += __shfl_xor(part1, 2);
            part0 += __shfl_xor(part0, 4); part1 += __shfl_xor(part1, 4);
            part0 += __shfl_xor(part0, 8); part1 += __shfl_xor(part1, 8);
            float p0 = __expf(part0), p1 = __expf(part1);
            lsum += p0 + p1;
            a0  += p0 * f00; a1v += p0 * f01; a2v += p0 * f02; a3  += p0 * f03;
            a0  += p1 * f10; a1v += p1 * f11; a2v += p1 * f12; a3  += p1 * f13;
        }
        if (e < end) {
            int s = cp[e];
            uint2 us = *reinterpret_cast<const uint2*>(frB + (((unsigned)s << 9) | laneoff));
            float fs0 = bflo(us.x), fs1 = bfhi(us.x), fs2 = bflo(us.y), fs3 = bfhi(us.y);
            float t, part;
            t = fs0 + fd0; part  = p6[r][0] * t + q4[r][0] * fabsf(t);
            t = fs1 + fd1; part += p6[r][1] * t; part += q4[r][1] * fabsf(t);
            t = fs2 + fd2; part += p6[r][2] * t; part += q4[r][2] * fabsf(t);
            t = fs3 + fd3; part += p6[r][3] * t; part += q4[r][3] * fabsf(t);
            part += __shfl_xor(part, 1);
            part += __shfl_xor(part, 2);
            part += __shfl_xor(part, 4);
            part += __shfl_xor(part, 8);
            float p = __expf(part);
            lsum += p;
            a0  += p * fs0; a1v += p * fs1; a2v += p * fs2; a3  += p * fs3;
        }
        float inv = 1.f / fmaxf(lsum, 1e-16f);
        t0 += a0 * inv; t1 += a1v * inv; t2 += a2v * inv; t3 += a3 * inv;
    }
    unsigned o = ((unsigned)n << 8) + (unsigned)c;
    uint2 xv = *reinterpret_cast<const uint2*>(xb + o);
    float v0 = fmaxf(t0 + 2.f * bflo(xv.x) + bsum0, 0.f);
    float v1 = fmaxf(t1 + 2.f * bfhi(xv.x) + bsum1, 0.f);
    float v2 = fmaxf(t2 + 2.f * bflo(xv.y) + bsum2, 0.f);
    float v3 = fmaxf(t3 + 2.f * bfhi(xv.y) + bsum3, 0.f);
    ushort4 ho;
    ho.x = f2bf(v0); ho.y = f2bf(v1); ho.z = f2bf(v2); ho.w = f2bf(v3);
    reinterpret_cast<ushort4*>(hb)[((unsigned)n << 6) + (unsigned)lane] = ho;
}

// ---------------- Layer-2 helpers ----------------
__global__ void build_wcat_bf(const float* __restrict__ W2, const float* __restrict__ Wres2,
                              unsigned short* __restrict__ Wcat) {
    int i = blockIdx.x * 256 + threadIdx.x;
    if (i >= 256 * 256) return;
    int o = i >> 8, k = i & 255;
    int sel = o >> 6, row = o & 63;
    int r = sel >> 1;
    const float* Wsrc = (sel & 1) ? Wres2 : W2;
    Wcat[i] = f2bf(Wsrc[((size_t)r * 64 + row) * 256 + k]);
}

__global__ void post2(const float* __restrict__ G, const float* __restrict__ b2,
                      unsigned short* __restrict__ feat2, float* __restrict__ base) {
    int i = blockIdx.x * 256 + threadIdx.x;
    if (i >= NN * 64) return;
    int n = i >> 6, d = i & 63;
    const float* g = G + (size_t)n * 256;
    feat2[i] = f2bf(g[d]);
    feat2[(size_t)NN * 64 + i] = f2bf(g[128 + d]);
    base[i] = g[64 + d] + g[192 + d] + b2[d] + b2[64 + d];
}

// ---------------- Layer-2 edge softmax + aggregation (H=1, D=64) ----------------
__global__ __launch_bounds__(64) void agg2_k(
    const unsigned short* __restrict__ feat2,  // [2][NN][64] bf16
    const float* __restrict__ base,
    const float* __restrict__ a2,              // [2][64]
    const int* __restrict__ rowptr, const int* __restrict__ csr,
    float* __restrict__ out)
{
    int n = blockIdx.x, lane = threadIdx.x;
    unsigned laneoff = (unsigned)lane * 2u;
    float av0 = a2[lane], av1 = a2[64 + lane];
    float p6a[2] = {0.6f * av0, 0.6f * av1};
    float q4a[2] = {0.4f * av0, 0.4f * av1};

    float tot = 0.f;
    #pragma unroll
    for (int r = 0; r < 2; ++r) {
        const char* frB = (const char*)(feat2 + (size_t)r * NN * 64);
        float fd = bf2f(*reinterpret_cast<const unsigned short*>(frB + (((unsigned)n << 7) | laneoff)));
        float lsum = 0.f, acc = 0.f;
        int beg = rowptr[r * (NN + 1) + n], end = rowptr[r * (NN + 1) + n + 1];
        const int* cp = csr + (size_t)r * EE;
        int e = beg;
        for (; e + 2 <= end; e += 2) {
            int s0 = cp[e], s1 = cp[e + 1];
            float fs0 = bf2f(*reinterpret_cast<const unsigned short*>(frB + (((unsigned)s0 << 7) | laneoff)));
            float fs1 = bf2f(*reinterpret_cast<const unsigned short*>(frB + (((unsigned)s1 << 7) | laneoff)));
            float ta = fs0 + fd, tb = fs1 + fd;
            float part0 = p6a[r] * ta + q4a[r] * fabsf(ta);
            float part1 = p6a[r] * tb + q4a[r] * fabsf(tb);
            part0 += __shfl_xor(part0, 1);  part1 += __shfl_xor(part1, 1);
            part0 += __shfl_xor(part0, 2);  part1 += __shfl_xor(part1, 2);
            part0 += __shfl_xor(part0, 4);  part1 += __shfl_xor(part1, 4);
            part0 += __shfl_xor(part0, 8);  part1 += __shfl_xor(part1, 8);
            part0 += __shfl_xor(part0, 16); part1 += __shfl_xor(part1, 16);
            part0 += __shfl_xor(part0, 32); part1 += __shfl_xor(part1, 32);
            float p0 = __expf(part0), p1 = __expf(part1);
            lsum += p0 + p1;
            acc += p0 * fs0;
            acc += p1 * fs1;
        }
        if (e < end) {
            int s = cp[e];
            float fs = bf2f(*reinterpret_cast<const unsigned short*>(frB + (((unsigned)s << 7) | laneoff)));
            float t = fs + fd;
            float part = p6a[r] * t + q4a[r] * fabsf(t);
            part += __shfl_xor(part, 1);
            part += __shfl_xor(part, 2);
            part += __shfl_xor(part, 4);
            part += __shfl_xor(part, 8);
            part += __shfl_xor(part, 16);
            part += __shfl_xor(part, 32);
            float p = __expf(part);
            lsum += p;
            acc += p * fs;
        }
        tot += acc / fmaxf(lsum, 1e-16f);
    }
    unsigned o = ((unsigned)n << 6) + (unsigned)lane;
    out[o] = fmaxf(tot + base[o], 0.f);
}

extern "C" void kernel_launch(void* const* d_in, const int* in_sizes, int n_in,
                              void* d_out, int out_size, void* d_ws, size_t ws_size,
                              hipStream_t stream) {
    (void)in_sizes; (void)n_in; (void)out_size; (void)ws_size;
    const float* x     = (const float*)d_in[0];
    const int*   src   = (const int*)d_in[1];
    const int*   dst   = (const int*)d_in[2];
    const float* W1    = (const float*)d_in[3];
    const float* a1    = (const float*)d_in[4];
    const float* b1    = (const float*)d_in[5];
    const float* W2    = (const float*)d_in[6];
    const float* a2    = (const float*)d_in[7];
    const float* b2    = (const float*)d_in[8];
    const float* Wres2 = (const float*)d_in[9];
    float* out = (float*)d_out;

    char* w = (char*)d_ws;
    size_t off = 0;
    auto alloc = [&](size_t bytes) -> void* {
        void* p = w + off;
        off = (off + bytes + 255) & ~(size_t)255;
        return p;
    };
    int* cursor = (int*)alloc((size_t)2 * NN * sizeof(int));
    int* rowptr = (int*)alloc((size_t)2 * (NN + 1) * sizeof(int));
    int* csr    = (int*)alloc((size_t)2 * EE * sizeof(int));
    int* rankb  = (int*)alloc((size_t)2 * EE * sizeof(int));
    unsigned short* feat1 = (unsigned short*)alloc((size_t)2 * NN * 256 * 2); // aliased as G (fp32 NN*256)
    float* G = (float*)feat1;
    unsigned short* xb = (unsigned short*)alloc((size_t)NN * 256 * 2);
    unsigned short* hb = (unsigned short*)alloc((size_t)NN * 256 * 2);
    unsigned short* W1b = (unsigned short*)alloc((size_t)2 * 256 * 256 * 2);
    unsigned short* Wcatb = (unsigned short*)alloc((size_t)256 * 256 * 2);
    unsigned short* feat2 = (unsigned short*)alloc((size_t)2 * NN * 64 * 2);
    float* base = (float*)alloc((size_t)NN * 64 * 4);

    // prep conversions + zero cursors
    hipMemsetAsync(cursor, 0, (size_t)2 * NN * sizeof(int), stream);
    cvt_f2bf<<<(NN * 256 / 4 + 255) / 256, 256, 0, stream>>>(x, xb, NN * 256 / 4);
    cvt_f2bf<<<(2 * 256 * 256 / 4 + 255) / 256, 256, 0, stream>>>(W1, W1b, 2 * 256 * 256 / 4);
    build_wcat_bf<<<(256 * 256 + 255) / 256, 256, 0, stream>>>(W2, Wres2, Wcatb);

    // Layer-1 GEMM co-scheduled with the edge-rank atomic pass
    gemm1_rank_k<<<G1BLK + RNKBLK, 256, 0, stream>>>(xb, W1b, feat1, dst, cursor, rankb);
    scan_k<<<2, 1024, 0, stream>>>(cursor, rowptr);
    place_k<<<RNKBLK, 256, 0, stream>>>(src, dst, rankb, rowptr, csr);

    agg1_k<<<NN, 64, 0, stream>>>(feat1, xb, a1, b1, rowptr, csr, hb);

    // Layer 2
    dim3 g2(391, 2, 1);
    gemm2_k<<<g2, 256, 0, stream>>>(hb, Wcatb, G);
    post2<<<(NN * 64 + 255) / 256, 256, 0, stream>>>(G, b2, feat2, base);
    agg2_k<<<NN, 64, 0, stream>>>(feat2, base, a2, rowptr, csr, out);
}

// Round 9
// 461.841 us; speedup vs baseline: 3.8636x; 1.0546x over previous
//
#include <hip/hip_runtime.h>
#include <hip/hip_bf16.h>

#define NN 50000
#define EE 800000

// mega1 block layout: interleave 1564 gemm blocks 1:4 with 6250 rank blocks,
// then 12500 cvt-x blocks, then 256 wcat blocks.
#define MG_INTER 7820      // 1564 * 5
#define MG_CVX0  7820
#define MG_CVXN  12500
#define MG_WC0   20320
#define MG_GRID  20576

typedef __attribute__((ext_vector_type(8))) short short8v;
typedef __attribute__((ext_vector_type(4))) float f32x4;

__device__ __forceinline__ float bf2f(unsigned short u) {
    return __uint_as_float(((unsigned int)u) << 16);
}
__device__ __forceinline__ float bflo(unsigned int u) {
    return __uint_as_float(u << 16);
}
__device__ __forceinline__ float bfhi(unsigned int u) {
    return __uint_as_float(u & 0xffff0000u);
}
__device__ __forceinline__ unsigned short f2bf(float f) {
    unsigned int u = __float_as_uint(f);
    unsigned int r = 0x7FFF + ((u >> 16) & 1);
    return (unsigned short)((u + r) >> 16);
}
__device__ __forceinline__ unsigned cvtpk(float lo, float hi) {
    unsigned r;
    asm("v_cvt_pk_bf16_f32 %0, %1, %2" : "=v"(r) : "v"(lo), "v"(hi));
    return r;
}

// ---------------- CSR: scan of counts -> rowptr ----------------
__global__ __launch_bounds__(1024) void scan_k(int* __restrict__ cursor, int* __restrict__ rowptr) {
    int r = blockIdx.x;
    int* cnt = cursor + r * NN;
    int* rp  = rowptr + r * (NN + 1);
    int tid = threadIdx.x;
    const int CH = (NN + 1023) / 1024;   // 49
    int beg = tid * CH;
    int end = beg + CH; if (end > NN) end = NN;
    int s = 0;
    for (int i = beg; i < end && i < NN; ++i) s += cnt[i];
    __shared__ int sums[1024];
    sums[tid] = s;
    __syncthreads();
    for (int offd = 1; offd < 1024; offd <<= 1) {
        int v = 0;
        if (tid >= offd) v = sums[tid - offd];
        __syncthreads();
        sums[tid] += v;
        __syncthreads();
    }
    int run = sums[tid] - s;
    for (int i = beg; i < end && i < NN; ++i) {
        int c = cnt[i];
        rp[i] = run;
        run += c;
    }
    if (tid == 1023) rp[NN] = sums[1023];
}

// place: no atomics — csr[rowptr[dst]+rank] = src
__global__ void place_k(const int* __restrict__ src, const int* __restrict__ dst,
                        const int* __restrict__ rank, const int* __restrict__ rowptr,
                        int* __restrict__ csr) {
    int i = blockIdx.x * 256 + threadIdx.x;
    if (i >= 2 * EE) return;
    int r = (i >= EE) ? 1 : 0;
    int d = dst[i];
    int pos = rowptr[r * (NN + 1) + d] + rank[i];
    csr[r * EE + pos] = src[i];
}

// ---------------- mega1: L1 GEMM (fp32 in, inline cvt) + rank + cvt-x + wcat ----------------
__global__ __launch_bounds__(256) void mega1_k(
    const float* __restrict__ X,       // [NN][256] fp32
    const float* __restrict__ W1,      // [2][256][256] fp32
    unsigned short* __restrict__ Cout, // [2][NN][256] bf16
    const int* __restrict__ dst, int* __restrict__ cursor, int* __restrict__ rank,
    unsigned short* __restrict__ xb,   // [NN][256] bf16 out
    const float* __restrict__ W2, const float* __restrict__ Wres2,
    unsigned short* __restrict__ Wcatb)
{
    __shared__ unsigned short sA[128][72];
    __shared__ unsigned short sB[128][72];
    int bid = blockIdx.x;
    int tid = threadIdx.x;

    if (bid >= MG_INTER) {
        if (bid < MG_WC0) {
            // cvt x -> xb (float4 -> 4 bf16 per thread)
            int i = (bid - MG_CVX0) * 256 + tid;   // < 3,200,000 exactly
            float4 v = reinterpret_cast<const float4*>(X)[i];
            uint2 o;
            o.x = cvtpk(v.x, v.y);
            o.y = cvtpk(v.z, v.w);
            reinterpret_cast<uint2*>(xb)[i] = o;
        } else {
            // build Wcat bf16
            int i = (bid - MG_WC0) * 256 + tid;    // < 65536
            int o = i >> 8, k = i & 255;
            int sel = o >> 6, row = o & 63, r = sel >> 1;
            const float* Wsrc = (sel & 1) ? Wres2 : W2;
            Wcatb[i] = f2bf(Wsrc[((size_t)r * 64 + row) * 256 + k]);
        }
        return;
    }

    int g = bid / 5, m = bid % 5;
    if (m != 0) {
        // rank block: one device atomic per edge, coalesced rank store
        int i = (g * 4 + (m - 1)) * 256 + tid;
        if (i < 2 * EE) {
            int r = (i >= EE) ? 1 : 0;
            rank[i] = atomicAdd(&cursor[r * NN + dst[i]], 1);
        }
        return;
    }

    // gemm block g : 128x128 tile, K=256
    const int K = 256;
    int bx = g % 391, by = (g / 391) & 1, bz = g / 782;
    int wid = tid >> 6, lane = tid & 63;
    int wr = wid >> 1, wc = wid & 1;
    int n0 = bx * 128;
    int o0 = by * 128;
    const float* Wr = W1 + (size_t)bz * 256 * 256;

    f32x4 acc[4][4] = {};

    for (int k0 = 0; k0 < K; k0 += 64) {
        #pragma unroll
        for (int p = 0; p < 4; ++p) {
            int flat = p * 256 + tid;
            int row = flat >> 3, k8 = (flat & 7) * 8;
            int gr = n0 + row;
            float4 xa = {0.f, 0.f, 0.f, 0.f}, xc = {0.f, 0.f, 0.f, 0.f};
            if (gr < NN) {
                const float* xp = X + (size_t)gr * K + k0 + k8;
                xa = *reinterpret_cast<const float4*>(xp);
                xc = *reinterpret_cast<const float4*>(xp + 4);
            }
            uint4 pa;
            pa.x = cvtpk(xa.x, xa.y); pa.y = cvtpk(xa.z, xa.w);
            pa.z = cvtpk(xc.x, xc.y); pa.w = cvtpk(xc.z, xc.w);
            *reinterpret_cast<uint4*>(&sA[row][k8]) = pa;
            const float* wp = Wr + (size_t)(o0 + row) * K + k0 + k8;
            float4 wa = *reinterpret_cast<const float4*>(wp);
            float4 wb = *reinterpret_cast<const float4*>(wp + 4);
            uint4 pb;
            pb.x = cvtpk(wa.x, wa.y); pb.y = cvtpk(wa.z, wa.w);
            pb.z = cvtpk(wb.x, wb.y); pb.w = cvtpk(wb.z, wb.w);
            *reinterpret_cast<uint4*>(&sB[row][k8]) = pb;
        }
        __syncthreads();
        #pragma unroll
        for (int kk = 0; kk < 2; ++kk) {
            short8v af[4], bf[4];
            int klo = kk * 32 + (lane >> 4) * 8;
            #pragma unroll
            for (int mm = 0; mm < 4; ++mm)
                af[mm] = *reinterpret_cast<const short8v*>(&sA[wr * 64 + mm * 16 + (lane & 15)][klo]);
            #pragma unroll
            for (int nn = 0; nn < 4; ++nn)
                bf[nn] = *reinterpret_cast<const short8v*>(&sB[wc * 64 + nn * 16 + (lane & 15)][klo]);
            #pragma unroll
            for (int mm = 0; mm < 4; ++mm)
                #pragma unroll
                for (int nn = 0; nn < 4; ++nn)
                    acc[mm][nn] = __builtin_amdgcn_mfma_f32_16x16x32_bf16(af[mm], bf[nn], acc[mm][nn], 0, 0, 0);
        }
        __syncthreads();
    }
    int col0 = o0 + wc * 64;
    int rbase = (lane >> 4) * 4;
    #pragma unroll
    for (int mm = 0; mm < 4; ++mm) {
        #pragma unroll
        for (int j = 0; j < 4; ++j) {
            int gr = n0 + wr * 64 + mm * 16 + rbase + j;
            if (gr >= NN) continue;
            #pragma unroll
            for (int nn = 0; nn < 4; ++nn) {
                int gc = col0 + nn * 16 + (lane & 15);
                size_t idx = (size_t)bz * NN * 256 + (size_t)gr * 256 + gc;
                Cout[idx] = f2bf(acc[mm][nn][j]);
            }
        }
    }
}

// ---------------- Layer-2 GEMM with fused post2 epilogue ----------------
// Output columns route per 64-col group: 0->feat2[0], 1->base0, 2->feat2[1], 3->base1.
__global__ __launch_bounds__(256) void gemm2_k(
    const unsigned short* __restrict__ A,   // [NN][256] bf16 (hb)
    const unsigned short* __restrict__ W,   // [256][256] bf16 (Wcat)
    unsigned short* __restrict__ feat2,     // [2][NN][64] bf16
    float* __restrict__ base0, float* __restrict__ base1)
{
    __shared__ unsigned short sA[128][72];
    __shared__ unsigned short sB[128][72];
    const int K = 256;
    int tid = threadIdx.x;
    int wid = tid >> 6, lane = tid & 63;
    int wr = wid >> 1, wc = wid & 1;
    int n0 = blockIdx.x * 128;
    int o0 = blockIdx.y * 128;

    f32x4 acc[4][4] = {};

    for (int k0 = 0; k0 < K; k0 += 64) {
        #pragma unroll
        for (int p = 0; p < 4; ++p) {
            int flat = p * 256 + tid;
            int row = flat >> 3, k8 = (flat & 7) * 8;
            int gr = n0 + row;
            short8v va = {0, 0, 0, 0, 0, 0, 0, 0};
            if (gr < NN) va = *reinterpret_cast<const short8v*>(A + (size_t)gr * K + k0 + k8);
            *reinterpret_cast<short8v*>(&sA[row][k8]) = va;
            short8v vb = *reinterpret_cast<const short8v*>(W + (size_t)(o0 + row) * K + k0 + k8);
            *reinterpret_cast<short8v*>(&sB[row][k8]) = vb;
        }
        __syncthreads();
        #pragma unroll
        for (int kk = 0; kk < 2; ++kk) {
            short8v af[4], bf[4];
            int klo = kk * 32 + (lane >> 4) * 8;
            #pragma unroll
            for (int m = 0; m < 4; ++m)
                af[m] = *reinterpret_cast<const short8v*>(&sA[wr * 64 + m * 16 + (lane & 15)][klo]);
            #pragma unroll
            for (int n = 0; n < 4; ++n)
                bf[n] = *reinterpret_cast<const short8v*>(&sB[wc * 64 + n * 16 + (lane & 15)][klo]);
            #pragma unroll
            for (int m = 0; m < 4; ++m)
                #pragma unroll
                for (int n = 0; n < 4; ++n)
                    acc[m][n] = __builtin_amdgcn_mfma_f32_16x16x32_bf16(af[m], bf[n], acc[m][n], 0, 0, 0);
        }
        __syncthreads();
    }
    int col0 = o0 + wc * 64;
    int sel = col0 >> 6;            // wave-uniform: 0..3
    int rbase = (lane >> 4) * 4;
    #pragma unroll
    for (int m = 0; m < 4; ++m) {
        #pragma unroll
        for (int j = 0; j < 4; ++j) {
            int gr = n0 + wr * 64 + m * 16 + rbase + j;
            if (gr >= NN) continue;
            #pragma unroll
            for (int n = 0; n < 4; ++n) {
                int d = n * 16 + (lane & 15);
                float v = acc[m][n][j];
                size_t o = (size_t)gr * 64 + d;
                if (sel == 0)      feat2[o] = f2bf(v);
                else if (sel == 1) base0[o] = v;
                else if (sel == 2) feat2[(size_t)NN * 64 + o] = f2bf(v);
                else               base1[o] = v;
            }
        }
    }
}

// ---------------- Layer-1 edge softmax + aggregation (H=4, D=64) ----------------
__global__ __launch_bounds__(64) void agg1_k(
    const unsigned short* __restrict__ feat,   // [2][NN][256] bf16
    const unsigned short* __restrict__ xb,     // [NN][256] bf16 (residual)
    const float* __restrict__ a1,              // [2][256]
    const float* __restrict__ b1,              // [2][256]
    const int* __restrict__ rowptr, const int* __restrict__ csr,
    unsigned short* __restrict__ hb)           // [NN][256] bf16 out
{
    int n = blockIdx.x, lane = threadIdx.x;
    unsigned laneoff = (unsigned)lane * 8u;
    int c = lane * 4;
    float4 av0v = *reinterpret_cast<const float4*>(a1 + c);
    float4 av1v = *reinterpret_cast<const float4*>(a1 + 256 + c);
    float p6[2][4], q4[2][4];
    p6[0][0] = 0.6f * av0v.x; q4[0][0] = 0.4f * av0v.x;
    p6[0][1] = 0.6f * av0v.y; q4[0][1] = 0.4f * av0v.y;
    p6[0][2] = 0.6f * av0v.z; q4[0][2] = 0.4f * av0v.z;
    p6[0][3] = 0.6f * av0v.w; q4[0][3] = 0.4f * av0v.w;
    p6[1][0] = 0.6f * av1v.x; q4[1][0] = 0.4f * av1v.x;
    p6[1][1] = 0.6f * av1v.y; q4[1][1] = 0.4f * av1v.y;
    p6[1][2] = 0.6f * av1v.z; q4[1][2] = 0.4f * av1v.z;
    p6[1][3] = 0.6f * av1v.w; q4[1][3] = 0.4f * av1v.w;
    float bsum0 = b1[c + 0] + b1[256 + c + 0];
    float bsum1 = b1[c + 1] + b1[256 + c + 1];
    float bsum2 = b1[c + 2] + b1[256 + c + 2];
    float bsum3 = b1[c + 3] + b1[256 + c + 3];

    float t0 = 0.f, t1 = 0.f, t2 = 0.f, t3 = 0.f;
    #pragma unroll
    for (int r = 0; r < 2; ++r) {
        const char* frB = (const char*)(feat + (size_t)r * NN * 256);
        uint2 ud = *reinterpret_cast<const uint2*>(frB + (((unsigned)n << 9) | laneoff));
        float fd0 = bflo(ud.x), fd1 = bfhi(ud.x), fd2 = bflo(ud.y), fd3 = bfhi(ud.y);
        float lsum = 0.f;
        float a0 = 0.f, a1v = 0.f, a2v = 0.f, a3 = 0.f;
        int beg = rowptr[r * (NN + 1) + n], end = rowptr[r * (NN + 1) + n + 1];
        const int* cp = csr + (size_t)r * EE;
        int e = beg;
        for (; e + 2 <= end; e += 2) {
            int s0 = cp[e], s1 = cp[e + 1];
            uint2 u0 = *reinterpret_cast<const uint2*>(frB + (((unsigned)s0 << 9) | laneoff));
            uint2 u1 = *reinterpret_cast<const uint2*>(frB + (((unsigned)s1 << 9) | laneoff));
            float f00 = bflo(u0.x), f01 = bfhi(u0.x), f02 = bflo(u0.y), f03 = bfhi(u0.y);
            float f10 = bflo(u1.x), f11 = bfhi(u1.x), f12 = bflo(u1.y), f13 = bfhi(u1.y);
            float t, part0, part1;
            t = f00 + fd0; part0  = p6[r][0] * t + q4[r][0] * fabsf(t);
            t = f01 + fd1; part0 += p6[r][1] * t; part0 += q4[r][1] * fabsf(t);
            t = f02 + fd2; part0 += p6[r][2] * t; part0 += q4[r][2] * fabsf(t);
            t = f03 + fd3; part0 += p6[r][3] * t; part0 += q4[r][3] * fabsf(t);
            t = f10 + fd0; part1  = p6[r][0] * t + q4[r][0] * fabsf(t);
            t = f11 + fd1; part1 += p6[r][1] * t; part1 += q4[r][1] * fabsf(t);
            t = f12 + fd2; part1 += p6[r][2] * t; part1 += q4[r][2] * fabsf(t);
            t = f13 + fd3; part1 += p6[r][3] * t; part1 += q4[r][3] * fabsf(t);
            part0 += __shfl_xor(part0, 1); part1 += __shfl_xor(part1, 1);
            part0 += __shfl_xor(part0, 2); part1 += __shfl_xor(part1, 2);
            part0 += __shfl_xor(part0, 4); part1 += __shfl_xor(part1, 4);
            part0 += __shfl_xor(part0, 8); part1 += __shfl_xor(part1, 8);
            float p0 = __expf(part0), p1 = __expf(part1);
            lsum += p0 + p1;
            a0  += p0 * f00; a1v += p0 * f01; a2v += p0 * f02; a3  += p0 * f03;
            a0  += p1 * f10; a1v += p1 * f11; a2v += p1 * f12; a3  += p1 * f13;
        }
        if (e < end) {
            int s = cp[e];
            uint2 us = *reinterpret_cast<const uint2*>(frB + (((unsigned)s << 9) | laneoff));
            float fs0 = bflo(us.x), fs1 = bfhi(us.x), fs2 = bflo(us.y), fs3 = bfhi(us.y);
            float t, part;
            t = fs0 + fd0; part  = p6[r][0] * t + q4[r][0] * fabsf(t);
            t = fs1 + fd1; part += p6[r][1] * t; part += q4[r][1] * fabsf(t);
            t = fs2 + fd2; part += p6[r][2] * t; part += q4[r][2] * fabsf(t);
            t = fs3 + fd3; part += p6[r][3] * t; part += q4[r][3] * fabsf(t);
            part += __shfl_xor(part, 1);
            part += __shfl_xor(part, 2);
            part += __shfl_xor(part, 4);
            part += __shfl_xor(part, 8);
            float p = __expf(part);
            lsum += p;
            a0  += p * fs0; a1v += p * fs1; a2v += p * fs2; a3  += p * fs3;
        }
        float inv = 1.f / fmaxf(lsum, 1e-16f);
        t0 += a0 * inv; t1 += a1v * inv; t2 += a2v * inv; t3 += a3 * inv;
    }
    unsigned o = ((unsigned)n << 8) + (unsigned)c;
    uint2 xv = *reinterpret_cast<const uint2*>(xb + o);
    float v0 = fmaxf(t0 + 2.f * bflo(xv.x) + bsum0, 0.f);
    float v1 = fmaxf(t1 + 2.f * bfhi(xv.x) + bsum1, 0.f);
    float v2 = fmaxf(t2 + 2.f * bflo(xv.y) + bsum2, 0.f);
    float v3 = fmaxf(t3 + 2.f * bfhi(xv.y) + bsum3, 0.f);
    ushort4 ho;
    ho.x = f2bf(v0); ho.y = f2bf(v1); ho.z = f2bf(v2); ho.w = f2bf(v3);
    reinterpret_cast<ushort4*>(hb)[((unsigned)n << 6) + (unsigned)lane] = ho;
}

// ---------------- Layer-2 edge softmax + aggregation (H=1, D=64), 4-edge ILP ----------------
__global__ __launch_bounds__(64) void agg2_k(
    const unsigned short* __restrict__ feat2,  // [2][NN][64] bf16
    const float* __restrict__ base0, const float* __restrict__ base1,
    const float* __restrict__ a2,              // [2][64]
    const float* __restrict__ b2,              // [2][64]
    const int* __restrict__ rowptr, const int* __restrict__ csr,
    float* __restrict__ out)
{
    int n = blockIdx.x, lane = threadIdx.x;
    unsigned laneoff = (unsigned)lane * 2u;
    float av0 = a2[lane], av1 = a2[64 + lane];
    float p6a[2] = {0.6f * av0, 0.6f * av1};
    float q4a[2] = {0.4f * av0, 0.4f * av1};
    float bs = b2[lane] + b2[64 + lane];

    float tot = 0.f;
    #pragma unroll
    for (int r = 0; r < 2; ++r) {
        const char* frB = (const char*)(feat2 + (size_t)r * NN * 64);
        float fd = bf2f(*reinterpret_cast<const unsigned short*>(frB + (((unsigned)n << 7) | laneoff)));
        float lsum = 0.f, acc = 0.f;
        int beg = rowptr[r * (NN + 1) + n], end = rowptr[r * (NN + 1) + n + 1];
        const int* cp = csr + (size_t)r * EE;
        int e = beg;
        for (; e + 4 <= end; e += 4) {
            int s0 = cp[e], s1 = cp[e + 1], s2 = cp[e + 2], s3 = cp[e + 3];
            float fs0 = bf2f(*reinterpret_cast<const unsigned short*>(frB + (((unsigned)s0 << 7) | laneoff)));
            float fs1 = bf2f(*reinterpret_cast<const unsigned short*>(frB + (((unsigned)s1 << 7) | laneoff)));
            float fs2 = bf2f(*reinterpret_cast<const unsigned short*>(frB + (((unsigned)s2 << 7) | laneoff)));
            float fs3 = bf2f(*reinterpret_cast<const unsigned short*>(frB + (((unsigned)s3 << 7) | laneoff)));
            float ta = fs0 + fd, tb = fs1 + fd, tc = fs2 + fd, td = fs3 + fd;
            float P0 = p6a[r] * ta + q4a[r] * fabsf(ta);
            float P1 = p6a[r] * tb + q4a[r] * fabsf(tb);
            float P2 = p6a[r] * tc + q4a[r] * fabsf(tc);
            float P3 = p6a[r] * td + q4a[r] * fabsf(td);
            P0 += __shfl_xor(P0, 1);  P1 += __shfl_xor(P1, 1);  P2 += __shfl_xor(P2, 1);  P3 += __shfl_xor(P3, 1);
            P0 += __shfl_xor(P0, 2);  P1 += __shfl_xor(P1, 2);  P2 += __shfl_xor(P2, 2);  P3 += __shfl_xor(P3, 2);
            P0 += __shfl_xor(P0, 4);  P1 += __shfl_xor(P1, 4);  P2 += __shfl_xor(P2, 4);  P3 += __shfl_xor(P3, 4);
            P0 += __shfl_xor(P0, 8);  P1 += __shfl_xor(P1, 8);  P2 += __shfl_xor(P2, 8);  P3 += __shfl_xor(P3, 8);
            P0 += __shfl_xor(P0, 16); P1 += __shfl_xor(P1, 16); P2 += __shfl_xor(P2, 16); P3 += __shfl_xor(P3, 16);
            P0 += __shfl_xor(P0, 32); P1 += __shfl_xor(P1, 32); P2 += __shfl_xor(P2, 32); P3 += __shfl_xor(P3, 32);
            float p0 = __expf(P0), p1 = __expf(P1), p2 = __expf(P2), p3 = __expf(P3);
            lsum += (p0 + p1) + (p2 + p3);
            acc += p0 * fs0; acc += p1 * fs1; acc += p2 * fs2; acc += p3 * fs3;
        }
        for (; e < end; ++e) {
            int s = cp[e];
            float fs = bf2f(*reinterpret_cast<const unsigned short*>(frB + (((unsigned)s << 7) | laneoff)));
            float t = fs + fd;
            float part = p6a[r] * t + q4a[r] * fabsf(t);
            part += __shfl_xor(part, 1);
            part += __shfl_xor(part, 2);
            part += __shfl_xor(part, 4);
            part += __shfl_xor(part, 8);
            part += __shfl_xor(part, 16);
            part += __shfl_xor(part, 32);
            float p = __expf(part);
            lsum += p;
            acc += p * fs;
        }
        tot += acc / fmaxf(lsum, 1e-16f);
    }
    unsigned o = ((unsigned)n << 6) + (unsigned)lane;
    out[o] = fmaxf(tot + base0[o] + base1[o] + bs, 0.f);
}

extern "C" void kernel_launch(void* const* d_in, const int* in_sizes, int n_in,
                              void* d_out, int out_size, void* d_ws, size_t ws_size,
                              hipStream_t stream) {
    (void)in_sizes; (void)n_in; (void)out_size; (void)ws_size;
    const float* x     = (const float*)d_in[0];
    const int*   src   = (const int*)d_in[1];
    const int*   dst   = (const int*)d_in[2];
    const float* W1    = (const float*)d_in[3];
    const float* a1    = (const float*)d_in[4];
    const float* b1    = (const float*)d_in[5];
    const float* W2    = (const float*)d_in[6];
    const float* a2    = (const float*)d_in[7];
    const float* b2    = (const float*)d_in[8];
    const float* Wres2 = (const float*)d_in[9];
    float* out = (float*)d_out;

    char* w = (char*)d_ws;
    size_t off = 0;
    auto alloc = [&](size_t bytes) -> void* {
        void* p = w + off;
        off = (off + bytes + 255) & ~(size_t)255;
        return p;
    };
    int* cursor = (int*)alloc((size_t)2 * NN * sizeof(int));
    int* rowptr = (int*)alloc((size_t)2 * (NN + 1) * sizeof(int));
    int* csr    = (int*)alloc((size_t)2 * EE * sizeof(int));
    int* rankb  = (int*)alloc((size_t)2 * EE * sizeof(int));
    unsigned short* feat1 = (unsigned short*)alloc((size_t)2 * NN * 256 * 2);
    unsigned short* xb = (unsigned short*)alloc((size_t)NN * 256 * 2);
    unsigned short* hb = (unsigned short*)alloc((size_t)NN * 256 * 2);
    unsigned short* Wcatb = (unsigned short*)alloc((size_t)256 * 256 * 2);
    unsigned short* feat2 = (unsigned short*)alloc((size_t)2 * NN * 64 * 2);
    float* base0 = (float*)alloc((size_t)NN * 64 * 4);
    float* base1 = (float*)alloc((size_t)NN * 64 * 4);

    hipMemsetAsync(cursor, 0, (size_t)2 * NN * sizeof(int), stream);

    // mega1: L1 GEMM + rank atomics + cvt-x + wcat, co-scheduled
    mega1_k<<<MG_GRID, 256, 0, stream>>>(x, W1, feat1, dst, cursor, rankb, xb, W2, Wres2, Wcatb);
    scan_k<<<2, 1024, 0, stream>>>(cursor, rowptr);
    place_k<<<(2 * EE + 255) / 256, 256, 0, stream>>>(src, dst, rankb, rowptr, csr);

    agg1_k<<<NN, 64, 0, stream>>>(feat1, xb, a1, b1, rowptr, csr, hb);

    // Layer 2: GEMM with fused post2 epilogue
    dim3 g2(391, 2, 1);
    gemm2_k<<<g2, 256, 0, stream>>>(hb, Wcatb, feat2, base0, base1);
    agg2_k<<<NN, 64, 0, stream>>>(feat2, base0, base1, a2, b2, rowptr, csr, out);
}